// Round 1
// baseline (218.660 us; speedup 1.0000x reference)
//
#include <hip/hip_runtime.h>

#define BH 64
#define SEQ 1024
#define DH 64
#define EPSV 1e-6f

typedef short short8 __attribute__((ext_vector_type(8)));
typedef float f32x4 __attribute__((ext_vector_type(4)));
typedef unsigned short u16;
typedef unsigned short u16x4 __attribute__((ext_vector_type(4)));

__device__ __forceinline__ u16 f2bf(float x) {
    unsigned u = __builtin_bit_cast(unsigned, x);
    u += 0x7fffu + ((u >> 16) & 1u);   // round-to-nearest-even
    return (u16)(u >> 16);
}
__device__ __forceinline__ float bf2f(u16 h) {
    unsigned u = ((unsigned)h) << 16;
    return __builtin_bit_cast(float, u);
}

// ---------------- prep 1: split Q,K into bf16 hi/lo ----------------
__global__ __launch_bounds__(256) void prep_split(
        const float* __restrict__ q, const float* __restrict__ k,
        u16* __restrict__ qh, u16* __restrict__ ql,
        u16* __restrict__ kh, u16* __restrict__ kl) {
    int t = blockIdx.x * blockDim.x + threadIdx.x;   // 1,048,576 threads, 4 elems each
    f32x4 qv = *(const f32x4*)(q + (size_t)t * 4);
    f32x4 kv = *(const f32x4*)(k + (size_t)t * 4);
    u16x4 qhh, qll, khh, kll;
#pragma unroll
    for (int j = 0; j < 4; ++j) {
        u16 h = f2bf(qv[j]); qhh[j] = h; qll[j] = f2bf(qv[j] - bf2f(h));
        u16 g = f2bf(kv[j]); khh[j] = g; kll[j] = f2bf(kv[j] - bf2f(g));
    }
    *(u16x4*)(qh + (size_t)t * 4) = qhh;
    *(u16x4*)(ql + (size_t)t * 4) = qll;
    *(u16x4*)(kh + (size_t)t * 4) = khh;
    *(u16x4*)(kl + (size_t)t * 4) = kll;
}

// ---------------- prep 2: V -> Vt[bh][d][s] bf16 ----------------
__global__ __launch_bounds__(256) void prep_vt(
        const float* __restrict__ v, u16* __restrict__ vt) {
    int t = blockIdx.x * blockDim.x + threadIdx.x;   // 1,048,576 threads
    int s4 = t & 255;
    int d  = (t >> 8) & 63;
    int bh = t >> 14;
    const float* src = v + ((size_t)bh * SEQ + s4 * 4) * DH + d;
    u16x4 o;
#pragma unroll
    for (int j = 0; j < 4; ++j) o[j] = f2bf(src[(size_t)j * DH]);
    *(u16x4*)(vt + ((size_t)bh * DH + d) * SEQ + s4 * 4) = o;
}

// ---------------- prep 3: mask -> bitfield [S][32] u32 ----------------
__global__ __launch_bounds__(256) void prep_mask(
        const int* __restrict__ mask, unsigned* __restrict__ bits) {
    int t = blockIdx.x * blockDim.x + threadIdx.x;   // 32768 threads
    int qr = t >> 5, w = t & 31;
    const int* src = mask + (size_t)qr * SEQ + w * 32;
    unsigned b = 0;
#pragma unroll
    for (int j = 0; j < 32; ++j) b |= (src[j] != 0 ? 1u : 0u) << j;
    bits[t] = b;
}

// ---------------- main: flash attention, 4 independent waves / block ----------------
__global__ __launch_bounds__(256) void attn_main(
        const u16* __restrict__ qh, const u16* __restrict__ ql,
        const u16* __restrict__ kh, const u16* __restrict__ kl,
        const u16* __restrict__ vt, const unsigned* __restrict__ mbits,
        float* __restrict__ out) {
    __shared__ u16 plds[4][16 * 40];   // per-wave 16 rows x 32 cols, stride 40 u16 (80B)

    const int wave = threadIdx.x >> 6;
    const int lane = threadIdx.x & 63;
    const int ln = lane & 15;          // tile column (n)
    const int lg = lane >> 4;          // 16-lane group (0..3)

    const int bh = blockIdx.x >> 4;
    const int qb = blockIdx.x & 15;
    const int qrow0 = qb * 64 + wave * 16;

    // Q fragments (A operand): row = ln, k-dim = c*32 + lg*8 + j
    const u16* qhp = qh + ((size_t)bh * SEQ + qrow0) * DH;
    const u16* qlp = ql + ((size_t)bh * SEQ + qrow0) * DH;
    short8 aqh[2], aql[2];
#pragma unroll
    for (int c = 0; c < 2; ++c) {
        aqh[c] = *(const short8*)(qhp + ln * DH + c * 32 + lg * 8);
        aql[c] = *(const short8*)(qlp + ln * DH + c * 32 + lg * 8);
    }

    const u16* khp = kh + (size_t)bh * SEQ * DH;
    const u16* klp = kl + (size_t)bh * SEQ * DH;
    const u16* vtp = vt + (size_t)bh * DH * SEQ;

    f32x4 O[4];
    float m[4], ls[4];
#pragma unroll
    for (int t = 0; t < 4; ++t) O[t] = (f32x4){0.f, 0.f, 0.f, 0.f};
#pragma unroll
    for (int i = 0; i < 4; ++i) { m[i] = -1e30f; ls[i] = 0.f; }

    const unsigned* mrow = mbits + (size_t)(qrow0 + lg * 4) * 32;
    u16* pl = (u16*)plds[wave];

    for (int kb = 0; kb < 32; ++kb) {
        // ---- QK^T: two 16x16 score tiles (split precision: 6 MFMA each) ----
        f32x4 sc[2];
#pragma unroll
        for (int h = 0; h < 2; ++h) {
            const u16* kb_h = khp + ((size_t)(kb * 32 + h * 16 + ln)) * DH + lg * 8;
            const u16* kb_l = klp + ((size_t)(kb * 32 + h * 16 + ln)) * DH + lg * 8;
            short8 bh0 = *(const short8*)(kb_h);
            short8 bh1 = *(const short8*)(kb_h + 32);
            short8 bl0 = *(const short8*)(kb_l);
            short8 bl1 = *(const short8*)(kb_l + 32);
            f32x4 s = (f32x4){0.f, 0.f, 0.f, 0.f};
            s = __builtin_amdgcn_mfma_f32_16x16x32_bf16(aqh[0], bh0, s, 0, 0, 0);
            s = __builtin_amdgcn_mfma_f32_16x16x32_bf16(aqh[1], bh1, s, 0, 0, 0);
            s = __builtin_amdgcn_mfma_f32_16x16x32_bf16(aql[0], bh0, s, 0, 0, 0);
            s = __builtin_amdgcn_mfma_f32_16x16x32_bf16(aql[1], bh1, s, 0, 0, 0);
            s = __builtin_amdgcn_mfma_f32_16x16x32_bf16(aqh[0], bl0, s, 0, 0, 0);
            s = __builtin_amdgcn_mfma_f32_16x16x32_bf16(aqh[1], bl1, s, 0, 0, 0);
            sc[h] = s;
        }

        // ---- mask + scale (C layout: col=ln, row=lg*4+i) ----
        unsigned mw[4];
#pragma unroll
        for (int i = 0; i < 4; ++i) mw[i] = mrow[i * 32 + kb];
#pragma unroll
        for (int h = 0; h < 2; ++h)
#pragma unroll
            for (int i = 0; i < 4; ++i) {
                float sv = sc[h][i] * 0.125f;
                sc[h][i] = ((mw[i] >> (h * 16 + ln)) & 1u) ? sv : EPSV;
            }

        // ---- online softmax ----
        float fr[4];
#pragma unroll
        for (int i = 0; i < 4; ++i) {
            float x = fmaxf(sc[0][i], sc[1][i]);
            x = fmaxf(x, __shfl_xor(x, 1));
            x = fmaxf(x, __shfl_xor(x, 2));
            x = fmaxf(x, __shfl_xor(x, 4));
            x = fmaxf(x, __shfl_xor(x, 8));
            float mn = fmaxf(m[i], x);
            fr[i] = __expf(m[i] - mn);
            m[i] = mn;
        }
        float p[2][4];
#pragma unroll
        for (int h = 0; h < 2; ++h)
#pragma unroll
            for (int i = 0; i < 4; ++i) p[h][i] = __expf(sc[h][i] - m[i]);
#pragma unroll
        for (int i = 0; i < 4; ++i) ls[i] = ls[i] * fr[i] + p[0][i] + p[1][i];
#pragma unroll
        for (int t = 0; t < 4; ++t)
#pragma unroll
            for (int i = 0; i < 4; ++i) O[t][i] *= fr[i];

        // ---- P (C layout) -> LDS -> A fragment layout ----
#pragma unroll
        for (int h = 0; h < 2; ++h)
#pragma unroll
            for (int i = 0; i < 4; ++i)
                pl[(lg * 4 + i) * 40 + h * 16 + ln] = f2bf(p[h][i]);
        short8 ap = *(const short8*)(pl + ln * 40 + lg * 8);

        // ---- PV: 4 d-tiles ----
#pragma unroll
        for (int t = 0; t < 4; ++t) {
            short8 bv = *(const short8*)(vtp + ((size_t)(t * 16 + ln)) * SEQ + kb * 32 + lg * 8);
            O[t] = __builtin_amdgcn_mfma_f32_16x16x32_bf16(ap, bv, O[t], 0, 0, 0);
        }
    }

    // ---- epilogue: reduce denominators across the 16 lanes, normalize, store ----
#pragma unroll
    for (int i = 0; i < 4; ++i) {
        float x = ls[i];
        x += __shfl_xor(x, 1);
        x += __shfl_xor(x, 2);
        x += __shfl_xor(x, 4);
        x += __shfl_xor(x, 8);
        ls[i] = 1.f / x;
    }
    float* op = out + ((size_t)bh * SEQ + qrow0) * DH;
#pragma unroll
    for (int t = 0; t < 4; ++t)
#pragma unroll
        for (int i = 0; i < 4; ++i)
            op[(lg * 4 + i) * DH + t * 16 + ln] = O[t][i] * ls[i];
}

extern "C" void kernel_launch(void* const* d_in, const int* in_sizes, int n_in,
                              void* d_out, int out_size, void* d_ws, size_t ws_size,
                              hipStream_t stream) {
    const float* q = (const float*)d_in[0];
    const float* k = (const float*)d_in[1];
    const float* v = (const float*)d_in[2];
    const int* mask = (const int*)d_in[3];
    float* out = (float*)d_out;

    char* w = (char*)d_ws;
    const size_t NQ = (size_t)BH * SEQ * DH;          // 4,194,304 elements
    u16* qh = (u16*)(w);
    u16* ql = (u16*)(w + 2 * NQ);
    u16* kh = (u16*)(w + 4 * NQ);
    u16* kl = (u16*)(w + 6 * NQ);
    u16* vt = (u16*)(w + 8 * NQ);
    unsigned* mbits = (unsigned*)(w + 10 * NQ);       // 128 KB

    prep_split<<<dim3((NQ / 4) / 256), dim3(256), 0, stream>>>(q, k, qh, ql, kh, kl);
    prep_vt<<<dim3((NQ / 4) / 256), dim3(256), 0, stream>>>(v, vt);
    prep_mask<<<dim3((SEQ * 32) / 256), dim3(256), 0, stream>>>(mask, mbits);
    attn_main<<<dim3(BH * (SEQ / 64)), dim3(256), 0, stream>>>(qh, ql, kh, kl, vt, mbits, out);
}

// Round 3
// 206.554 us; speedup vs baseline: 1.0586x; 1.0586x over previous
//
#include <hip/hip_runtime.h>

#define BH 64
#define SEQ 1024
#define DH 64
#define EPSV 1e-6f
#define MFIX 8.3f   /* fixed softmax reference: p = e^(s - MFIX); max |s|<8 w.h.p., exact for any MFIX */

typedef short short8 __attribute__((ext_vector_type(8)));
typedef float f32x4 __attribute__((ext_vector_type(4)));
typedef unsigned short u16;
typedef unsigned short u16x4 __attribute__((ext_vector_type(4)));

__device__ __forceinline__ u16 f2bf(float x) {
    unsigned u = __builtin_bit_cast(unsigned, x);
    u += 0x7fffu + ((u >> 16) & 1u);   // round-to-nearest-even
    return (u16)(u >> 16);
}
__device__ __forceinline__ float bf2f(u16 h) {
    unsigned u = ((unsigned)h) << 16;
    return __builtin_bit_cast(float, u);
}

// ---------------- prep 1: split Q,K into bf16 hi/lo ----------------
__global__ __launch_bounds__(256) void prep_split(
        const float* __restrict__ q, const float* __restrict__ k,
        u16* __restrict__ qh, u16* __restrict__ ql,
        u16* __restrict__ kh, u16* __restrict__ kl) {
    int t = blockIdx.x * blockDim.x + threadIdx.x;   // 1,048,576 threads, 4 elems each
    f32x4 qv = *(const f32x4*)(q + (size_t)t * 4);
    f32x4 kv = *(const f32x4*)(k + (size_t)t * 4);
    u16x4 qhh, qll, khh, kll;
#pragma unroll
    for (int j = 0; j < 4; ++j) {
        u16 h = f2bf(qv[j]); qhh[j] = h; qll[j] = f2bf(qv[j] - bf2f(h));
        u16 g = f2bf(kv[j]); khh[j] = g; kll[j] = f2bf(kv[j] - bf2f(g));
    }
    *(u16x4*)(qh + (size_t)t * 4) = qhh;
    *(u16x4*)(ql + (size_t)t * 4) = qll;
    *(u16x4*)(kh + (size_t)t * 4) = khh;
    *(u16x4*)(kl + (size_t)t * 4) = kll;
}

// ---------------- prep 2: V -> Vt[bh][d][s] bf16 via LDS tile transpose ----------------
__global__ __launch_bounds__(256) void prep_vt(
        const float* __restrict__ v, u16* __restrict__ vt) {
    __shared__ u16 tile[64][65];
    const int bh = blockIdx.x >> 4;
    const int st = blockIdx.x & 15;          // 64-row s-tile
    const int t = threadIdx.x;

    // load phase: coalesced
    const int sl = t >> 2, c = t & 3;
    const float* src = v + ((size_t)bh * SEQ + st * 64 + sl) * DH + c * 16;
#pragma unroll
    for (int q = 0; q < 4; ++q) {
        f32x4 x = *(const f32x4*)(src + q * 4);
#pragma unroll
        for (int j = 0; j < 4; ++j) tile[sl][c * 16 + q * 4 + j] = f2bf(x[j]);
    }
    __syncthreads();

    // store phase: coalesced
    const int d = t >> 2, scn = t & 3;
    u16* dst = vt + ((size_t)bh * DH + d) * SEQ + st * 64 + scn * 16;
    short8 o0, o1;
#pragma unroll
    for (int j = 0; j < 8; ++j) o0[j] = (short)tile[scn * 16 + j][d];
#pragma unroll
    for (int j = 0; j < 8; ++j) o1[j] = (short)tile[scn * 16 + 8 + j][d];
    *(short8*)dst = o0;
    *(short8*)(dst + 8) = o1;
}

// ---------------- prep 3: mask -> bitfield [S][32] u32 ----------------
__global__ __launch_bounds__(256) void prep_mask(
        const int* __restrict__ mask, unsigned* __restrict__ bits) {
    int t = blockIdx.x * blockDim.x + threadIdx.x;   // 32768 threads
    int qr = t >> 5, w = t & 31;
    const int* src = mask + (size_t)qr * SEQ + w * 32;
    unsigned b = 0;
#pragma unroll
    for (int j = 0; j < 32; ++j) b |= (src[j] != 0 ? 1u : 0u) << j;
    bits[t] = b;
}

// ---------------- main: flash attention, fixed-m softmax + K-prefetch ----------------

#define LOADK(KB, KR) do { \
    _Pragma("unroll") \
    for (int h_ = 0; h_ < 2; ++h_) { \
        const u16* ph_ = khp + (size_t)((KB) * 32 + h_ * 16) * DH; \
        const u16* pq_ = klp + (size_t)((KB) * 32 + h_ * 16) * DH; \
        KR[h_ * 4 + 0] = *(const short8*)(ph_); \
        KR[h_ * 4 + 1] = *(const short8*)(ph_ + 32); \
        KR[h_ * 4 + 2] = *(const short8*)(pq_); \
        KR[h_ * 4 + 3] = *(const short8*)(pq_ + 32); \
    } \
} while (0)

#define BODY(KB, CUR, NXT, LBUF, MW0, MW1, MW2, MW3, KPF) do { \
    LOADK(KPF, NXT); \
    short8 bv0_ = *(const short8*)(vtp + (size_t)( 0) * SEQ + (KB) * 32); \
    short8 bv1_ = *(const short8*)(vtp + (size_t)(16) * SEQ + (KB) * 32); \
    short8 bv2_ = *(const short8*)(vtp + (size_t)(32) * SEQ + (KB) * 32); \
    short8 bv3_ = *(const short8*)(vtp + (size_t)(48) * SEQ + (KB) * 32); \
    f32x4 sa_, sb_, sc0_, sc1_; \
    sa_ = (f32x4){0.f,0.f,0.f,0.f}; sb_ = (f32x4){0.f,0.f,0.f,0.f}; \
    sa_ = __builtin_amdgcn_mfma_f32_16x16x32_bf16(aqh0, CUR[0], sa_, 0, 0, 0); \
    sb_ = __builtin_amdgcn_mfma_f32_16x16x32_bf16(aqh1, CUR[1], sb_, 0, 0, 0); \
    sa_ = __builtin_amdgcn_mfma_f32_16x16x32_bf16(aql0, CUR[0], sa_, 0, 0, 0); \
    sb_ = __builtin_amdgcn_mfma_f32_16x16x32_bf16(aql1, CUR[1], sb_, 0, 0, 0); \
    sa_ = __builtin_amdgcn_mfma_f32_16x16x32_bf16(aqh0, CUR[2], sa_, 0, 0, 0); \
    sb_ = __builtin_amdgcn_mfma_f32_16x16x32_bf16(aqh1, CUR[3], sb_, 0, 0, 0); \
    sc0_ = sa_ + sb_; \
    sa_ = (f32x4){0.f,0.f,0.f,0.f}; sb_ = (f32x4){0.f,0.f,0.f,0.f}; \
    sa_ = __builtin_amdgcn_mfma_f32_16x16x32_bf16(aqh0, CUR[4], sa_, 0, 0, 0); \
    sb_ = __builtin_amdgcn_mfma_f32_16x16x32_bf16(aqh1, CUR[5], sb_, 0, 0, 0); \
    sa_ = __builtin_amdgcn_mfma_f32_16x16x32_bf16(aql0, CUR[4], sa_, 0, 0, 0); \
    sb_ = __builtin_amdgcn_mfma_f32_16x16x32_bf16(aql1, CUR[5], sb_, 0, 0, 0); \
    sa_ = __builtin_amdgcn_mfma_f32_16x16x32_bf16(aqh0, CUR[6], sa_, 0, 0, 0); \
    sb_ = __builtin_amdgcn_mfma_f32_16x16x32_bf16(aqh1, CUR[7], sb_, 0, 0, 0); \
    sc1_ = sa_ + sb_; \
    unsigned mr_[4] = { (MW0) >> ln, (MW1) >> ln, (MW2) >> ln, (MW3) >> ln }; \
    _Pragma("unroll") \
    for (int i_ = 0; i_ < 4; ++i_) { \
        float s0_ = (mr_[i_] & 1u)       ? (sc0_[i_] * 0.125f - MFIX) : (EPSV - MFIX); \
        float s1_ = (mr_[i_] & 0x10000u) ? (sc1_[i_] * 0.125f - MFIX) : (EPSV - MFIX); \
        float p0_ = __expf(s0_); \
        float p1_ = __expf(s1_); \
        ls[i_] += p0_ + p1_; \
        (LBUF)[(lg * 4 + i_) * 40 + ln]      = f2bf(p0_); \
        (LBUF)[(lg * 4 + i_) * 40 + 16 + ln] = f2bf(p1_); \
    } \
    short8 ap_ = *(const short8*)((LBUF) + ln * 40 + lg * 8); \
    O0 = __builtin_amdgcn_mfma_f32_16x16x32_bf16(ap_, bv0_, O0, 0, 0, 0); \
    O1 = __builtin_amdgcn_mfma_f32_16x16x32_bf16(ap_, bv1_, O1, 0, 0, 0); \
    O2 = __builtin_amdgcn_mfma_f32_16x16x32_bf16(ap_, bv2_, O2, 0, 0, 0); \
    O3 = __builtin_amdgcn_mfma_f32_16x16x32_bf16(ap_, bv3_, O3, 0, 0, 0); \
} while (0)

__global__ __launch_bounds__(256) void attn_main(
        const u16* __restrict__ qh, const u16* __restrict__ ql,
        const u16* __restrict__ kh, const u16* __restrict__ kl,
        const u16* __restrict__ vt, const unsigned* __restrict__ mbits,
        float* __restrict__ out) {
    __shared__ u16 plds[4][2][16 * 40];   // per-wave double-buffered P tile

    const int wave = threadIdx.x >> 6;
    const int lane = threadIdx.x & 63;
    const int ln = lane & 15;          // tile column (n)
    const int lg = lane >> 4;          // 16-lane group (0..3)

    const int bh = blockIdx.x >> 4;
    const int qb = blockIdx.x & 15;
    const int qrow0 = qb * 64 + wave * 16;

    // Q fragments (A operand): row = ln, k-dim = lg*8 + j (+32 for second half)
    const u16* qhp = qh + ((size_t)bh * SEQ + qrow0 + ln) * DH + lg * 8;
    const u16* qlp = ql + ((size_t)bh * SEQ + qrow0 + ln) * DH + lg * 8;
    short8 aqh0 = *(const short8*)(qhp);
    short8 aqh1 = *(const short8*)(qhp + 32);
    short8 aql0 = *(const short8*)(qlp);
    short8 aql1 = *(const short8*)(qlp + 32);

    const u16* khp = kh + ((size_t)bh * SEQ + ln) * DH + lg * 8;
    const u16* klp = kl + ((size_t)bh * SEQ + ln) * DH + lg * 8;
    const u16* vtp = vt + ((size_t)bh * DH + ln) * SEQ + lg * 8;

    f32x4 O0 = {0.f,0.f,0.f,0.f}, O1 = {0.f,0.f,0.f,0.f};
    f32x4 O2 = {0.f,0.f,0.f,0.f}, O3 = {0.f,0.f,0.f,0.f};
    float ls[4] = {0.f, 0.f, 0.f, 0.f};

    const unsigned* mrow = mbits + (size_t)(qrow0 + lg * 4) * 32;
    u16* lb0 = (u16*)plds[wave][0];
    u16* lb1 = (u16*)plds[wave][1];

    short8 kA[8], kB[8];
    LOADK(0, kA);

#pragma unroll 1
    for (int kb = 0; kb < 32; kb += 2) {
        uint2 md0 = *(const uint2*)(mrow + 0 * 32 + kb);
        uint2 md1 = *(const uint2*)(mrow + 1 * 32 + kb);
        uint2 md2 = *(const uint2*)(mrow + 2 * 32 + kb);
        uint2 md3 = *(const uint2*)(mrow + 3 * 32 + kb);
        int kpf2 = (kb + 2 < 32) ? kb + 2 : 31;
        BODY(kb,     kA, kB, lb0, md0.x, md1.x, md2.x, md3.x, kb + 1);
        BODY(kb + 1, kB, kA, lb1, md0.y, md1.y, md2.y, md3.y, kpf2);
    }

    // ---- epilogue: reduce denominators across the 16 lanes, normalize, store ----
#pragma unroll
    for (int i = 0; i < 4; ++i) {
        float x = ls[i];
        x += __shfl_xor(x, 1);
        x += __shfl_xor(x, 2);
        x += __shfl_xor(x, 4);
        x += __shfl_xor(x, 8);
        ls[i] = 1.f / x;
    }
    float* op = out + ((size_t)bh * SEQ + qrow0) * DH;
#pragma unroll
    for (int i = 0; i < 4; ++i) {
        op[(lg * 4 + i) * DH +  0 + ln] = O0[i] * ls[i];
        op[(lg * 4 + i) * DH + 16 + ln] = O1[i] * ls[i];
        op[(lg * 4 + i) * DH + 32 + ln] = O2[i] * ls[i];
        op[(lg * 4 + i) * DH + 48 + ln] = O3[i] * ls[i];
    }
}

extern "C" void kernel_launch(void* const* d_in, const int* in_sizes, int n_in,
                              void* d_out, int out_size, void* d_ws, size_t ws_size,
                              hipStream_t stream) {
    const float* q = (const float*)d_in[0];
    const float* k = (const float*)d_in[1];
    const float* v = (const float*)d_in[2];
    const int* mask = (const int*)d_in[3];
    float* out = (float*)d_out;

    char* w = (char*)d_ws;
    const size_t NQ = (size_t)BH * SEQ * DH;          // 4,194,304 elements
    u16* qh = (u16*)(w);
    u16* ql = (u16*)(w + 2 * NQ);
    u16* kh = (u16*)(w + 4 * NQ);
    u16* kl = (u16*)(w + 6 * NQ);
    u16* vt = (u16*)(w + 8 * NQ);
    unsigned* mbits = (unsigned*)(w + 10 * NQ);       // 128 KB

    prep_split<<<dim3((NQ / 4) / 256), dim3(256), 0, stream>>>(q, k, qh, ql, kh, kl);
    prep_vt<<<dim3(BH * 16), dim3(256), 0, stream>>>(v, vt);
    prep_mask<<<dim3((SEQ * 32) / 256), dim3(256), 0, stream>>>(mask, mbits);
    attn_main<<<dim3(BH * (SEQ / 64)), dim3(256), 0, stream>>>(qh, ql, kh, kl, vt, mbits, out);
}

// Round 4
// 81.724 us; speedup vs baseline: 2.6756x; 2.5275x over previous
//
#include <hip/hip_runtime.h>

#define BH 64
#define SEQ 1024
#define DH 64
#define EPSV 1e-6f
#define MFIX 8.3f   /* fixed softmax reference: p = e^(s - MFIX); exact for any m, scores |s|<8 w.h.p. */

typedef short short8 __attribute__((ext_vector_type(8)));
typedef float f32x4 __attribute__((ext_vector_type(4)));
typedef unsigned short u16;
typedef unsigned short u16x4 __attribute__((ext_vector_type(4)));

__device__ __forceinline__ u16 f2bf(float x) {
    unsigned u = __builtin_bit_cast(unsigned, x);
    u += 0x7fffu + ((u >> 16) & 1u);   // round-to-nearest-even
    return (u16)(u >> 16);
}
__device__ __forceinline__ float bf2f(u16 h) {
    unsigned u = ((unsigned)h) << 16;
    return __builtin_bit_cast(float, u);
}
__device__ __forceinline__ void gload16(const void* g, void* l) {
    __builtin_amdgcn_global_load_lds(
        (const __attribute__((address_space(1))) void*)g,
        (__attribute__((address_space(3))) void*)l, 16, 0, 0);
}

// ---------------- prep 1: split Q,K into bf16 hi/lo ----------------
__global__ __launch_bounds__(256) void prep_split(
        const float* __restrict__ q, const float* __restrict__ k,
        u16* __restrict__ qh, u16* __restrict__ ql,
        u16* __restrict__ kh, u16* __restrict__ kl) {
    int t = blockIdx.x * blockDim.x + threadIdx.x;
    f32x4 qv = *(const f32x4*)(q + (size_t)t * 4);
    f32x4 kv = *(const f32x4*)(k + (size_t)t * 4);
    u16x4 qhh, qll, khh, kll;
#pragma unroll
    for (int j = 0; j < 4; ++j) {
        u16 h = f2bf(qv[j]); qhh[j] = h; qll[j] = f2bf(qv[j] - bf2f(h));
        u16 g = f2bf(kv[j]); khh[j] = g; kll[j] = f2bf(kv[j] - bf2f(g));
    }
    *(u16x4*)(qh + (size_t)t * 4) = qhh;
    *(u16x4*)(ql + (size_t)t * 4) = qll;
    *(u16x4*)(kh + (size_t)t * 4) = khh;
    *(u16x4*)(kl + (size_t)t * 4) = kll;
}

// ---------------- prep 2: V -> Vt[bh][d][s] bf16 via LDS tile transpose ----------------
__global__ __launch_bounds__(256) void prep_vt(
        const float* __restrict__ v, u16* __restrict__ vt) {
    __shared__ u16 tile[64][65];
    const int bh = blockIdx.x >> 4;
    const int st = blockIdx.x & 15;
    const int t = threadIdx.x;

    const int sl = t >> 2, c = t & 3;
    const float* src = v + ((size_t)bh * SEQ + st * 64 + sl) * DH + c * 16;
#pragma unroll
    for (int q = 0; q < 4; ++q) {
        f32x4 x = *(const f32x4*)(src + q * 4);
#pragma unroll
        for (int j = 0; j < 4; ++j) tile[sl][c * 16 + q * 4 + j] = f2bf(x[j]);
    }
    __syncthreads();

    const int d = t >> 2, scn = t & 3;
    u16* dst = vt + ((size_t)bh * DH + d) * SEQ + st * 64 + scn * 16;
    short8 o0, o1;
#pragma unroll
    for (int j = 0; j < 8; ++j) o0[j] = (short)tile[scn * 16 + j][d];
#pragma unroll
    for (int j = 0; j < 8; ++j) o1[j] = (short)tile[scn * 16 + 8 + j][d];
    *(short8*)dst = o0;
    *(short8*)(dst + 8) = o1;
}

// ---------------- prep 3: mask -> bitfield [S][32] u32 ----------------
__global__ __launch_bounds__(256) void prep_mask(
        const int* __restrict__ mask, unsigned* __restrict__ bits) {
    int t = blockIdx.x * blockDim.x + threadIdx.x;
    int qr = t >> 5, w = t & 31;
    const int* src = mask + (size_t)qr * SEQ + w * 32;
    unsigned b = 0;
#pragma unroll
    for (int j = 0; j < 32; ++j) b |= (src[j] != 0 ? 1u : 0u) << j;
    bits[t] = b;
}

// ---------------- main: cooperative LDS-staged flash attention ----------------
// LDS buffer layout (per 12 KB buffer): [0,4K) kh tile 32 rows x 128B (slot-swizzled)
//                                       [4K,8K) kl tile (same swizzle)
//                                       [8K,12K) vt slice 64 d-rows x 64B (linear)
// K swizzle: 16B slot s at row r stored at slot s ^ (r&7)  (involution; stage pre-swizzles
// the GLOBAL source so global_load_lds can write linearly — rule both-sides-or-neither).

#define STAGE(KB, BUF) do { \
    char* lb_ = lds_k + (BUF) * 12288; \
    size_t ro_ = (size_t)((KB) * 32 + krow_s) * 128 + kcol_s; \
    gload16(khg + ro_, lb_); \
    gload16(klg + ro_, lb_ + 4096); \
    gload16(vtg + (size_t)vd_s * (SEQ * 2) + (size_t)(KB) * 64 + vcol_s, lb_ + 8192); \
} while (0)

__global__ __launch_bounds__(256) void attn_main(
        const u16* __restrict__ qh, const u16* __restrict__ ql,
        const u16* __restrict__ kh, const u16* __restrict__ kl,
        const u16* __restrict__ vt, const unsigned* __restrict__ mbits,
        float* __restrict__ out) {
    __shared__ __align__(16) unsigned char smem[2 * 12288];
    __shared__ u16 plds[4][16 * 40];

    const int wave = threadIdx.x >> 6;
    const int lane = threadIdx.x & 63;
    const int ln = lane & 15;
    const int lg = lane >> 4;

    const int bh = blockIdx.x >> 4;
    const int qb = blockIdx.x & 15;
    const int qrow0 = qb * 64 + wave * 16;

    // Q fragments (A operand): row = ln, k-dim = lg*8+j (+32 for second reg)
    const u16* qhp = qh + ((size_t)bh * SEQ + qrow0 + ln) * DH + lg * 8;
    const u16* qlp = ql + ((size_t)bh * SEQ + qrow0 + ln) * DH + lg * 8;
    short8 aqh0 = *(const short8*)(qhp);
    short8 aqh1 = *(const short8*)(qhp + 32);
    short8 aql0 = *(const short8*)(qlp);
    short8 aql1 = *(const short8*)(qlp + 32);

    const char* khg = (const char*)(kh + (size_t)bh * SEQ * DH);
    const char* klg = (const char*)(kl + (size_t)bh * SEQ * DH);
    const char* vtg = (const char*)(vt + (size_t)bh * DH * SEQ);

    // staging: this wave covers 1KB of each section; lane -> (row, slot)
    const int krow_s = wave * 8 + (lane >> 3);                       // local K row
    const size_t kcol_s = (size_t)(((lane & 7) ^ (lane >> 3)) << 4); // pre-swizzled source col
    const int vd_s = wave * 16 + (lane >> 2);                        // vt d-row
    const size_t vcol_s = (size_t)((lane & 3) << 4);
    char* lds_k = (char*)smem + wave * 1024;

    // ds_read offsets (loop-invariant): K swizzled, V linear
    const int swz = ln & 7;
    const int oh0a = ln * 128 + ((lg ^ swz) << 4);
    const int oh0b = ln * 128 + (((4 + lg) ^ swz) << 4);
    const int oh1a = (16 + ln) * 128 + ((lg ^ swz) << 4);
    const int oh1b = (16 + ln) * 128 + (((4 + lg) ^ swz) << 4);
    const int oV0 = 8192 + (0 * 16 + ln) * 64 + (lg << 4);
    const int oV1 = 8192 + (1 * 16 + ln) * 64 + (lg << 4);
    const int oV2 = 8192 + (2 * 16 + ln) * 64 + (lg << 4);
    const int oV3 = 8192 + (3 * 16 + ln) * 64 + (lg << 4);

    f32x4 O0 = {0.f,0.f,0.f,0.f}, O1 = {0.f,0.f,0.f,0.f};
    f32x4 O2 = {0.f,0.f,0.f,0.f}, O3 = {0.f,0.f,0.f,0.f};
    float ls[4] = {0.f, 0.f, 0.f, 0.f};

    const unsigned* mrow = mbits + (size_t)(qrow0 + lg * 4) * 32;
    u16* pl = (u16*)plds[wave];

    unsigned mw[4];
#pragma unroll
    for (int i = 0; i < 4; ++i) mw[i] = mrow[i * 32];
    STAGE(0, 0);
    __syncthreads();

#pragma unroll 1
    for (int kb = 0; kb < 32; ++kb) {
        const int cur = kb & 1;
        unsigned mn[4];
        if (kb < 31) {
            STAGE(kb + 1, cur ^ 1);
#pragma unroll
            for (int i = 0; i < 4; ++i) mn[i] = mrow[i * 32 + kb + 1];
        }

        const char* bb = (const char*)smem + cur * 12288;

        // ---- QK^T tile h=0 ----
        short8 kh0a = *(const short8*)(bb + oh0a);
        short8 kh0b = *(const short8*)(bb + oh0b);
        short8 kl0a = *(const short8*)(bb + 4096 + oh0a);
        short8 kl0b = *(const short8*)(bb + 4096 + oh0b);
        f32x4 sa = {0.f,0.f,0.f,0.f}, sb = {0.f,0.f,0.f,0.f};
        sa = __builtin_amdgcn_mfma_f32_16x16x32_bf16(aqh0, kh0a, sa, 0, 0, 0);
        sb = __builtin_amdgcn_mfma_f32_16x16x32_bf16(aqh1, kh0b, sb, 0, 0, 0);
        sa = __builtin_amdgcn_mfma_f32_16x16x32_bf16(aql0, kh0a, sa, 0, 0, 0);
        sb = __builtin_amdgcn_mfma_f32_16x16x32_bf16(aql1, kh0b, sb, 0, 0, 0);
        sa = __builtin_amdgcn_mfma_f32_16x16x32_bf16(aqh0, kl0a, sa, 0, 0, 0);
        sb = __builtin_amdgcn_mfma_f32_16x16x32_bf16(aqh1, kl0b, sb, 0, 0, 0);
        f32x4 sc0 = sa + sb;

        // ---- QK^T tile h=1 ----
        short8 kh1a = *(const short8*)(bb + oh1a);
        short8 kh1b = *(const short8*)(bb + oh1b);
        short8 kl1a = *(const short8*)(bb + 4096 + oh1a);
        short8 kl1b = *(const short8*)(bb + 4096 + oh1b);
        sa = (f32x4){0.f,0.f,0.f,0.f}; sb = (f32x4){0.f,0.f,0.f,0.f};
        sa = __builtin_amdgcn_mfma_f32_16x16x32_bf16(aqh0, kh1a, sa, 0, 0, 0);
        sb = __builtin_amdgcn_mfma_f32_16x16x32_bf16(aqh1, kh1b, sb, 0, 0, 0);
        sa = __builtin_amdgcn_mfma_f32_16x16x32_bf16(aql0, kh1a, sa, 0, 0, 0);
        sb = __builtin_amdgcn_mfma_f32_16x16x32_bf16(aql1, kh1b, sb, 0, 0, 0);
        sa = __builtin_amdgcn_mfma_f32_16x16x32_bf16(aqh0, kl1a, sa, 0, 0, 0);
        sb = __builtin_amdgcn_mfma_f32_16x16x32_bf16(aqh1, kl1b, sb, 0, 0, 0);
        f32x4 sc1 = sa + sb;

        // ---- mask + fixed-m softmax (C layout: col=ln, row=lg*4+i) ----
#pragma unroll
        for (int i = 0; i < 4; ++i) {
            unsigned mr = mw[i] >> ln;
            float s0 = (mr & 1u)       ? (sc0[i] * 0.125f - MFIX) : (EPSV - MFIX);
            float s1 = (mr & 0x10000u) ? (sc1[i] * 0.125f - MFIX) : (EPSV - MFIX);
            float p0 = __expf(s0);
            float p1 = __expf(s1);
            ls[i] += p0 + p1;
            pl[(lg * 4 + i) * 40 + ln]      = f2bf(p0);
            pl[(lg * 4 + i) * 40 + 16 + ln] = f2bf(p1);
        }
        short8 ap = *(const short8*)(pl + ln * 40 + lg * 8);

        // ---- PV: 4 d-tiles from LDS V slice ----
        short8 v0 = *(const short8*)(bb + oV0);
        short8 v1 = *(const short8*)(bb + oV1);
        short8 v2 = *(const short8*)(bb + oV2);
        short8 v3 = *(const short8*)(bb + oV3);
        O0 = __builtin_amdgcn_mfma_f32_16x16x32_bf16(ap, v0, O0, 0, 0, 0);
        O1 = __builtin_amdgcn_mfma_f32_16x16x32_bf16(ap, v1, O1, 0, 0, 0);
        O2 = __builtin_amdgcn_mfma_f32_16x16x32_bf16(ap, v2, O2, 0, 0, 0);
        O3 = __builtin_amdgcn_mfma_f32_16x16x32_bf16(ap, v3, O3, 0, 0, 0);

        __syncthreads();   // drains stage vmcnt + guards buffer swap
        if (kb < 31) {
#pragma unroll
            for (int i = 0; i < 4; ++i) mw[i] = mn[i];
        }
    }

    // ---- epilogue ----
#pragma unroll
    for (int i = 0; i < 4; ++i) {
        float x = ls[i];
        x += __shfl_xor(x, 1);
        x += __shfl_xor(x, 2);
        x += __shfl_xor(x, 4);
        x += __shfl_xor(x, 8);
        ls[i] = 1.f / x;
    }
    float* op = out + ((size_t)bh * SEQ + qrow0) * DH;
#pragma unroll
    for (int i = 0; i < 4; ++i) {
        op[(lg * 4 + i) * DH +  0 + ln] = O0[i] * ls[i];
        op[(lg * 4 + i) * DH + 16 + ln] = O1[i] * ls[i];
        op[(lg * 4 + i) * DH + 32 + ln] = O2[i] * ls[i];
        op[(lg * 4 + i) * DH + 48 + ln] = O3[i] * ls[i];
    }
}

extern "C" void kernel_launch(void* const* d_in, const int* in_sizes, int n_in,
                              void* d_out, int out_size, void* d_ws, size_t ws_size,
                              hipStream_t stream) {
    const float* q = (const float*)d_in[0];
    const float* k = (const float*)d_in[1];
    const float* v = (const float*)d_in[2];
    const int* mask = (const int*)d_in[3];
    float* out = (float*)d_out;

    char* w = (char*)d_ws;
    const size_t NQ = (size_t)BH * SEQ * DH;
    u16* qh = (u16*)(w);
    u16* ql = (u16*)(w + 2 * NQ);
    u16* kh = (u16*)(w + 4 * NQ);
    u16* kl = (u16*)(w + 6 * NQ);
    u16* vt = (u16*)(w + 8 * NQ);
    unsigned* mbits = (unsigned*)(w + 10 * NQ);

    prep_split<<<dim3((NQ / 4) / 256), dim3(256), 0, stream>>>(q, k, qh, ql, kh, kl);
    prep_vt<<<dim3(BH * 16), dim3(256), 0, stream>>>(v, vt);
    prep_mask<<<dim3((SEQ * 32) / 256), dim3(256), 0, stream>>>(mask, mbits);
    attn_main<<<dim3(BH * (SEQ / 64)), dim3(256), 0, stream>>>(qh, ql, kh, kl, vt, mbits, out);
}

// Round 5
// 76.671 us; speedup vs baseline: 2.8519x; 1.0659x over previous
//
#include <hip/hip_runtime.h>

#define BH 64
#define SEQ 1024
#define DH 64
#define EPSV 1e-6f
#define MFIX 8.3f   /* fixed softmax reference: p = e^(s - MFIX); exact for any m, scores |s|<8 w.h.p. */

typedef short short8 __attribute__((ext_vector_type(8)));
typedef float f32x4 __attribute__((ext_vector_type(4)));
typedef float f32x16 __attribute__((ext_vector_type(16)));
typedef unsigned u32x4 __attribute__((ext_vector_type(4)));
typedef unsigned short u16;
typedef unsigned short u16x4 __attribute__((ext_vector_type(4)));

__device__ __forceinline__ u16 f2bf(float x) {
    unsigned u = __builtin_bit_cast(unsigned, x);
    u += 0x7fffu + ((u >> 16) & 1u);   // round-to-nearest-even
    return (u16)(u >> 16);
}
__device__ __forceinline__ float bf2f(u16 h) {
    unsigned u = ((unsigned)h) << 16;
    return __builtin_bit_cast(float, u);
}
__device__ __forceinline__ void gload16(const void* g, void* l) {
    __builtin_amdgcn_global_load_lds(
        (const __attribute__((address_space(1))) void*)g,
        (__attribute__((address_space(3))) void*)l, 16, 0, 0);
}

// ---------------- prep 1: split Q,K into bf16 hi/lo ----------------
__global__ __launch_bounds__(256) void prep_split(
        const float* __restrict__ q, const float* __restrict__ k,
        u16* __restrict__ qh, u16* __restrict__ ql,
        u16* __restrict__ kh, u16* __restrict__ kl) {
    int t = blockIdx.x * blockDim.x + threadIdx.x;
    f32x4 qv = *(const f32x4*)(q + (size_t)t * 4);
    f32x4 kv = *(const f32x4*)(k + (size_t)t * 4);
    u16x4 qhh, qll, khh, kll;
#pragma unroll
    for (int j = 0; j < 4; ++j) {
        u16 h = f2bf(qv[j]); qhh[j] = h; qll[j] = f2bf(qv[j] - bf2f(h));
        u16 g = f2bf(kv[j]); khh[j] = g; kll[j] = f2bf(kv[j] - bf2f(g));
    }
    *(u16x4*)(qh + (size_t)t * 4) = qhh;
    *(u16x4*)(ql + (size_t)t * 4) = qll;
    *(u16x4*)(kh + (size_t)t * 4) = khh;
    *(u16x4*)(kl + (size_t)t * 4) = kll;
}

// ---------------- prep 2: V -> Vt[bh][d][s] bf16 via LDS tile transpose ----------------
__global__ __launch_bounds__(256) void prep_vt(
        const float* __restrict__ v, u16* __restrict__ vt) {
    __shared__ u16 tile[64][65];
    const int bh = blockIdx.x >> 4;
    const int st = blockIdx.x & 15;
    const int t = threadIdx.x;

    const int sl = t >> 2, c = t & 3;
    const float* src = v + ((size_t)bh * SEQ + st * 64 + sl) * DH + c * 16;
#pragma unroll
    for (int q = 0; q < 4; ++q) {
        f32x4 x = *(const f32x4*)(src + q * 4);
#pragma unroll
        for (int j = 0; j < 4; ++j) tile[sl][c * 16 + q * 4 + j] = f2bf(x[j]);
    }
    __syncthreads();

    const int d = t >> 2, scn = t & 3;
    u16* dst = vt + ((size_t)bh * DH + d) * SEQ + st * 64 + scn * 16;
    short8 o0, o1;
#pragma unroll
    for (int j = 0; j < 8; ++j) o0[j] = (short)tile[scn * 16 + j][d];
#pragma unroll
    for (int j = 0; j < 8; ++j) o1[j] = (short)tile[scn * 16 + 8 + j][d];
    *(short8*)dst = o0;
    *(short8*)(dst + 8) = o1;
}

// ---------------- prep 3: mask -> bitfield [S][32] u32 ----------------
__global__ __launch_bounds__(256) void prep_mask(
        const int* __restrict__ mask, unsigned* __restrict__ bits) {
    int t = blockIdx.x * blockDim.x + threadIdx.x;
    int qr = t >> 5, w = t & 31;
    const int* src = mask + (size_t)qr * SEQ + w * 32;
    unsigned b = 0;
#pragma unroll
    for (int j = 0; j < 32; ++j) b |= (src[j] != 0 ? 1u : 0u) << j;
    bits[t] = b;
}

// ---------------- main: 32x32 MFMA, swapped QK^T, in-register softmax ----------------
// Block = 128 threads (2 waves); wave owns 32 q-rows. KVBLK = 32 keys/iter.
// LDS per buffer (12KB): [0,4K) kh 32x128B (slot^row&7 swizzle), [4K,8K) kl,
// [8K,12K) vt 64 d-rows x 64B (slot^((d>>1)&3) swizzle). Double buffered.
// Swizzles applied BOTH sides: pre-swizzled global source (gload_lds writes
// linearly) + swizzled ds_read offset.

#define STAGE(KB, BUF) do { \
    const size_t ko_ = (size_t)(KB) << 12; \
    const size_t vo_ = (size_t)(KB) << 6; \
    char* db_ = dbase + (BUF) * 12288; \
    gload16(khs + ko_,         db_); \
    gload16(khs + ko_ + 2048,  db_ + 2048); \
    gload16(kls + ko_,         db_ + 4096); \
    gload16(kls + ko_ + 2048,  db_ + 6144); \
    gload16(vts + vo_,         db_ + 8192); \
    gload16(vts + vo_ + 65536, db_ + 10240); \
} while (0)

__global__ __launch_bounds__(128, 2) void attn_main(
        const u16* __restrict__ qh, const u16* __restrict__ ql,
        const u16* __restrict__ kh, const u16* __restrict__ kl,
        const u16* __restrict__ vt, const unsigned* __restrict__ mbits,
        float* __restrict__ out) {
    __shared__ __align__(16) unsigned char smem[2 * 12288 + 256];
    float* lsd = (float*)(smem + 2 * 12288);

    const int lane = threadIdx.x & 63;
    const int wave = threadIdx.x >> 6;
    const int l5 = lane & 31;
    const int hi = lane >> 5;

    // XCD-aware swizzle: XCD x serves bh in [8x, 8x+8) (K/V set 3MB < 4MB L2)
    const int bid = blockIdx.x;
    const int bh = ((bid & 7) << 3) | (bid >> 7);
    const int qb = (bid >> 3) & 15;
    const int qrow0 = qb * 64 + wave * 32;

    // Q B-fragments: B[k][n]: n = l5 = q-row, k = c*16 + hi*8 + j
    const u16* qhp = qh + ((size_t)bh * SEQ + qrow0 + l5) * DH + hi * 8;
    const u16* qlp = ql + ((size_t)bh * SEQ + qrow0 + l5) * DH + hi * 8;
    short8 bqh[4], bql[4];
#pragma unroll
    for (int c = 0; c < 4; ++c) {
        bqh[c] = *(const short8*)(qhp + c * 16);
        bql[c] = *(const short8*)(qlp + c * 16);
    }

    // staging sources (pre-swizzled per-lane)
    const char* khg = (const char*)(kh + (size_t)bh * SEQ * DH);
    const char* klg = (const char*)(kl + (size_t)bh * SEQ * DH);
    const char* vtg = (const char*)(vt + (size_t)bh * DH * SEQ);
    const size_t koffs = (size_t)(wave * 8 + (lane >> 3)) * 128
                       + (size_t)(((lane & 7) ^ (lane >> 3)) << 4);
    const size_t voffs = (size_t)(wave * 16 + (lane >> 2)) * (SEQ * 2)
                       + (size_t)(((lane & 3) ^ ((lane >> 3) & 3)) << 4);
    const char* khs = khg + koffs;
    const char* kls = klg + koffs;
    const char* vts = vtg + voffs;
    char* dbase = (char*)smem + wave * 1024;

    // LDS read offsets: K A-frag row=l5(key), slot=(c*2+hi)^(l5&7);
    // V B-frag row=t*32+l5(d), slot=(c*2+hi)^((l5>>1)&3)
    int koff[4], voff0[2], voff1[2];
#pragma unroll
    for (int c = 0; c < 4; ++c)
        koff[c] = l5 * 128 + ((((c << 1) | hi) ^ (l5 & 7)) << 4);
#pragma unroll
    for (int c = 0; c < 2; ++c) {
        const int s = (((c << 1) | hi) ^ ((l5 >> 1) & 3)) << 4;
        voff0[c] = 8192 + l5 * 64 + s;
        voff1[c] = 8192 + (32 + l5) * 64 + s;
    }

    const unsigned* mp = mbits + (size_t)(qrow0 + l5) * 32;

    f32x16 O0, O1;
#pragma unroll
    for (int r = 0; r < 16; ++r) { O0[r] = 0.f; O1[r] = 0.f; }
    float ls = 0.f;

    unsigned mwc = mp[0];
    STAGE(0, 0);
    __syncthreads();

#pragma unroll 1
    for (int kb = 0; kb < 32; ++kb) {
        const char* bb = (const char*)smem + (kb & 1) * 12288;
        unsigned mwn = 0;
        if (kb < 31) {
            STAGE(kb + 1, (kb & 1) ^ 1);
            mwn = mp[kb + 1];
        }

        // ---- QK^T swapped: S^T = K * Q^T, split precision, 2 acc chains ----
        f32x16 a0, a1;
#pragma unroll
        for (int r = 0; r < 16; ++r) { a0[r] = 0.f; a1[r] = 0.f; }
        {
            short8 kc, kcl;
            kc  = *(const short8*)(bb + koff[0]);
            kcl = *(const short8*)(bb + 4096 + koff[0]);
            a0 = __builtin_amdgcn_mfma_f32_32x32x16_bf16(kc,  bqh[0], a0, 0, 0, 0);
            a0 = __builtin_amdgcn_mfma_f32_32x32x16_bf16(kc,  bql[0], a0, 0, 0, 0);
            a0 = __builtin_amdgcn_mfma_f32_32x32x16_bf16(kcl, bqh[0], a0, 0, 0, 0);
            kc  = *(const short8*)(bb + koff[1]);
            kcl = *(const short8*)(bb + 4096 + koff[1]);
            a1 = __builtin_amdgcn_mfma_f32_32x32x16_bf16(kc,  bqh[1], a1, 0, 0, 0);
            a1 = __builtin_amdgcn_mfma_f32_32x32x16_bf16(kc,  bql[1], a1, 0, 0, 0);
            a1 = __builtin_amdgcn_mfma_f32_32x32x16_bf16(kcl, bqh[1], a1, 0, 0, 0);
            kc  = *(const short8*)(bb + koff[2]);
            kcl = *(const short8*)(bb + 4096 + koff[2]);
            a0 = __builtin_amdgcn_mfma_f32_32x32x16_bf16(kc,  bqh[2], a0, 0, 0, 0);
            a0 = __builtin_amdgcn_mfma_f32_32x32x16_bf16(kc,  bql[2], a0, 0, 0, 0);
            a0 = __builtin_amdgcn_mfma_f32_32x32x16_bf16(kcl, bqh[2], a0, 0, 0, 0);
            kc  = *(const short8*)(bb + koff[3]);
            kcl = *(const short8*)(bb + 4096 + koff[3]);
            a1 = __builtin_amdgcn_mfma_f32_32x32x16_bf16(kc,  bqh[3], a1, 0, 0, 0);
            a1 = __builtin_amdgcn_mfma_f32_32x32x16_bf16(kc,  bql[3], a1, 0, 0, 0);
            a1 = __builtin_amdgcn_mfma_f32_32x32x16_bf16(kcl, bqh[3], a1, 0, 0, 0);
        }

        // ---- mask + fixed-m softmax, fully in-register ----
        // C^T layout: col = l5 = q-row; reg r -> key (r&3) + 4*hi + 8*(r>>2)
        const unsigned wm = mwc >> (hi << 2);
        float p[16];
#pragma unroll
        for (int r = 0; r < 16; ++r) {
            float arg = fmaf(a0[r] + a1[r], 0.125f, -MFIX);
            arg = ((wm >> ((r & 3) + ((r >> 2) << 3))) & 1u) ? arg : (EPSV - MFIX);
            float pe = __expf(arg);
            p[r] = pe;
            ls += pe;
        }

        // ---- T12: cvt_pk + permlane32_swap -> PV A-frags (natural key order) ----
        unsigned x0, x1, y0, y1;
        asm("v_cvt_pk_bf16_f32 %0, %1, %2" : "=v"(x0) : "v"(p[0]), "v"(p[1]));
        asm("v_cvt_pk_bf16_f32 %0, %1, %2" : "=v"(x1) : "v"(p[2]), "v"(p[3]));
        asm("v_cvt_pk_bf16_f32 %0, %1, %2" : "=v"(y0) : "v"(p[4]), "v"(p[5]));
        asm("v_cvt_pk_bf16_f32 %0, %1, %2" : "=v"(y1) : "v"(p[6]), "v"(p[7]));
        asm volatile("v_permlane32_swap_b32 %0, %1" : "+v"(x0), "+v"(y0));
        asm volatile("v_permlane32_swap_b32 %0, %1" : "+v"(x1), "+v"(y1));
        u32x4 pw0; pw0[0] = x0; pw0[1] = x1; pw0[2] = y0; pw0[3] = y1;
        short8 pa0 = __builtin_bit_cast(short8, pw0);

        unsigned x2, x3, y2, y3;
        asm("v_cvt_pk_bf16_f32 %0, %1, %2" : "=v"(x2) : "v"(p[8]),  "v"(p[9]));
        asm("v_cvt_pk_bf16_f32 %0, %1, %2" : "=v"(x3) : "v"(p[10]), "v"(p[11]));
        asm("v_cvt_pk_bf16_f32 %0, %1, %2" : "=v"(y2) : "v"(p[12]), "v"(p[13]));
        asm("v_cvt_pk_bf16_f32 %0, %1, %2" : "=v"(y3) : "v"(p[14]), "v"(p[15]));
        asm volatile("v_permlane32_swap_b32 %0, %1" : "+v"(x2), "+v"(y2));
        asm volatile("v_permlane32_swap_b32 %0, %1" : "+v"(x3), "+v"(y3));
        u32x4 pw1; pw1[0] = x2; pw1[1] = x3; pw1[2] = y2; pw1[3] = y3;
        short8 pa1 = __builtin_bit_cast(short8, pw1);

        // ---- PV: O[q][d] += P * V ----
        short8 v00 = *(const short8*)(bb + voff0[0]);
        short8 v01 = *(const short8*)(bb + voff0[1]);
        short8 v10 = *(const short8*)(bb + voff1[0]);
        short8 v11 = *(const short8*)(bb + voff1[1]);
        O0 = __builtin_amdgcn_mfma_f32_32x32x16_bf16(pa0, v00, O0, 0, 0, 0);
        O0 = __builtin_amdgcn_mfma_f32_32x32x16_bf16(pa1, v01, O0, 0, 0, 0);
        O1 = __builtin_amdgcn_mfma_f32_32x32x16_bf16(pa0, v10, O1, 0, 0, 0);
        O1 = __builtin_amdgcn_mfma_f32_32x32x16_bf16(pa1, v11, O1, 0, 0, 0);

        __syncthreads();   // drains stage vmcnt + guards buffer swap
        mwc = mwn;
    }

    // ---- epilogue: combine half-wave denominators via LDS, normalize ----
    const float lst = ls + __shfl_xor(ls, 32);
    if (hi == 0) lsd[wave * 32 + l5] = lst;
    __syncthreads();
    float* op = out + ((size_t)bh * SEQ + qrow0) * DH;
#pragma unroll
    for (int r = 0; r < 16; ++r) {
        const int qr = (r & 3) + ((r >> 2) << 3) + (hi << 2);
        const float iv = 1.f / lsd[wave * 32 + qr];
        op[(size_t)qr * DH + l5] = O0[r] * iv;
        op[(size_t)qr * DH + 32 + l5] = O1[r] * iv;
    }
}

extern "C" void kernel_launch(void* const* d_in, const int* in_sizes, int n_in,
                              void* d_out, int out_size, void* d_ws, size_t ws_size,
                              hipStream_t stream) {
    const float* q = (const float*)d_in[0];
    const float* k = (const float*)d_in[1];
    const float* v = (const float*)d_in[2];
    const int* mask = (const int*)d_in[3];
    float* out = (float*)d_out;

    char* w = (char*)d_ws;
    const size_t NQ = (size_t)BH * SEQ * DH;
    u16* qh = (u16*)(w);
    u16* ql = (u16*)(w + 2 * NQ);
    u16* kh = (u16*)(w + 4 * NQ);
    u16* kl = (u16*)(w + 6 * NQ);
    u16* vt = (u16*)(w + 8 * NQ);
    unsigned* mbits = (unsigned*)(w + 10 * NQ);

    prep_split<<<dim3((NQ / 4) / 256), dim3(256), 0, stream>>>(q, k, qh, ql, kh, kl);
    prep_vt<<<dim3(BH * 16), dim3(256), 0, stream>>>(v, vt);
    prep_mask<<<dim3((SEQ * 32) / 256), dim3(256), 0, stream>>>(mask, mbits);
    attn_main<<<dim3(BH * (SEQ / 64)), dim3(128), 0, stream>>>(qh, ql, kh, kl, vt, mbits, out);
}

// Round 6
// 73.977 us; speedup vs baseline: 2.9558x; 1.0364x over previous
//
#include <hip/hip_runtime.h>

#define BH 64
#define SEQ 1024
#define DH 64
#define EPSV 1e-6f
#define MFIX 8.3f   /* fixed softmax reference: p = e^(s - MFIX); exact for any m, scores |s|<8 w.h.p. */
#define EPSC (EPSV - MFIX)

typedef short short8 __attribute__((ext_vector_type(8)));
typedef float f32x4 __attribute__((ext_vector_type(4)));
typedef float f32x16 __attribute__((ext_vector_type(16)));
typedef unsigned u32x4 __attribute__((ext_vector_type(4)));
typedef unsigned short u16;
typedef unsigned short u16x4 __attribute__((ext_vector_type(4)));

__device__ __forceinline__ u16 f2bf(float x) {
    unsigned u = __builtin_bit_cast(unsigned, x);
    u += 0x7fffu + ((u >> 16) & 1u);   // round-to-nearest-even
    return (u16)(u >> 16);
}
__device__ __forceinline__ float bf2f(u16 h) {
    unsigned u = ((unsigned)h) << 16;
    return __builtin_bit_cast(float, u);
}
__device__ __forceinline__ void gload16(const void* g, void* l) {
    __builtin_amdgcn_global_load_lds(
        (const __attribute__((address_space(1))) void*)g,
        (__attribute__((address_space(3))) void*)l, 16, 0, 0);
}

// ---------------- prep 1: split Q,K into bf16 hi/lo ----------------
__global__ __launch_bounds__(256) void prep_split(
        const float* __restrict__ q, const float* __restrict__ k,
        u16* __restrict__ qh, u16* __restrict__ ql,
        u16* __restrict__ kh, u16* __restrict__ kl) {
    int t = blockIdx.x * blockDim.x + threadIdx.x;
    f32x4 qv = *(const f32x4*)(q + (size_t)t * 4);
    f32x4 kv = *(const f32x4*)(k + (size_t)t * 4);
    u16x4 qhh, qll, khh, kll;
#pragma unroll
    for (int j = 0; j < 4; ++j) {
        u16 h = f2bf(qv[j]); qhh[j] = h; qll[j] = f2bf(qv[j] - bf2f(h));
        u16 g = f2bf(kv[j]); khh[j] = g; kll[j] = f2bf(kv[j] - bf2f(g));
    }
    *(u16x4*)(qh + (size_t)t * 4) = qhh;
    *(u16x4*)(ql + (size_t)t * 4) = qll;
    *(u16x4*)(kh + (size_t)t * 4) = khh;
    *(u16x4*)(kl + (size_t)t * 4) = kll;
}

// ---------------- prep 2: V -> Vt[bh][d][s] bf16 via LDS tile transpose ----------------
__global__ __launch_bounds__(256) void prep_vt(
        const float* __restrict__ v, u16* __restrict__ vt) {
    __shared__ u16 tile[64][65];
    const int bh = blockIdx.x >> 4;
    const int st = blockIdx.x & 15;
    const int t = threadIdx.x;

    const int sl = t >> 2, c = t & 3;
    const float* src = v + ((size_t)bh * SEQ + st * 64 + sl) * DH + c * 16;
#pragma unroll
    for (int q = 0; q < 4; ++q) {
        f32x4 x = *(const f32x4*)(src + q * 4);
#pragma unroll
        for (int j = 0; j < 4; ++j) tile[sl][c * 16 + q * 4 + j] = f2bf(x[j]);
    }
    __syncthreads();

    const int d = t >> 2, scn = t & 3;
    u16* dst = vt + ((size_t)bh * DH + d) * SEQ + st * 64 + scn * 16;
    short8 o0, o1;
#pragma unroll
    for (int j = 0; j < 8; ++j) o0[j] = (short)tile[scn * 16 + j][d];
#pragma unroll
    for (int j = 0; j < 8; ++j) o1[j] = (short)tile[scn * 16 + 8 + j][d];
    *(short8*)dst = o0;
    *(short8*)(dst + 8) = o1;
}

// ---------------- prep 3: mask -> bitfield [S][32] u32 ----------------
__global__ __launch_bounds__(256) void prep_mask(
        const int* __restrict__ mask, unsigned* __restrict__ bits) {
    int t = blockIdx.x * blockDim.x + threadIdx.x;
    int qr = t >> 5, w = t & 31;
    const int* src = mask + (size_t)qr * SEQ + w * 32;
    unsigned b = 0;
#pragma unroll
    for (int j = 0; j < 32; ++j) b |= (src[j] != 0 ? 1u : 0u) << j;
    bits[t] = b;
}

// ---------------- main: 32x32 MFMA, pipelined (QK(kb+1) || softmax(kb)) ----------------
// 3 LDS buffers x 12KB: [0,4K) kh 32x128B (slot^row&7), [4K,8K) kl, [8K,12K) vt 64x64B.
// Per iter kb: vmcnt(0) [1-iter-old loads] -> s_barrier -> stage(kb+2) ->
//              QK(kb+1) MFMA -> softmax(kb) VALU -> PV(kb) + ls-MFMA.
// Buffers touched in iter kb: {kb, kb+1, kb+2} distinct mod 3; barrier bounds skew. Safe.

#define STAGE(KB, BUF) do { \
    const size_t ko_ = (size_t)(KB) << 12; \
    const size_t vo_ = (size_t)(KB) << 6; \
    char* db_ = dbase + (size_t)(BUF) * 12288; \
    gload16(khs + ko_,         db_); \
    gload16(khs + ko_ + 2048,  db_ + 2048); \
    gload16(kls + ko_,         db_ + 4096); \
    gload16(kls + ko_ + 2048,  db_ + 6144); \
    gload16(vts + vo_,         db_ + 8192); \
    gload16(vts + vo_ + 65536, db_ + 10240); \
} while (0)

#define QK(BB, SN0, SN1) do { \
    const char* bq_ = (BB); \
    short8 kc0_ = *(const short8*)(bq_ + koff[0]); \
    short8 kd0_ = *(const short8*)(bq_ + 4096 + koff[0]); \
    short8 kc1_ = *(const short8*)(bq_ + koff[1]); \
    short8 kd1_ = *(const short8*)(bq_ + 4096 + koff[1]); \
    short8 kc2_ = *(const short8*)(bq_ + koff[2]); \
    short8 kd2_ = *(const short8*)(bq_ + 4096 + koff[2]); \
    short8 kc3_ = *(const short8*)(bq_ + koff[3]); \
    short8 kd3_ = *(const short8*)(bq_ + 4096 + koff[3]); \
    SN0 = __builtin_amdgcn_mfma_f32_32x32x16_bf16(kc0_, bqh0, ZR, 0, 0, 0); \
    SN1 = __builtin_amdgcn_mfma_f32_32x32x16_bf16(kc1_, bqh1, ZR, 0, 0, 0); \
    SN0 = __builtin_amdgcn_mfma_f32_32x32x16_bf16(kc0_, bql0, SN0, 0, 0, 0); \
    SN1 = __builtin_amdgcn_mfma_f32_32x32x16_bf16(kc1_, bql1, SN1, 0, 0, 0); \
    SN0 = __builtin_amdgcn_mfma_f32_32x32x16_bf16(kd0_, bqh0, SN0, 0, 0, 0); \
    SN1 = __builtin_amdgcn_mfma_f32_32x32x16_bf16(kd1_, bqh1, SN1, 0, 0, 0); \
    SN0 = __builtin_amdgcn_mfma_f32_32x32x16_bf16(kc2_, bqh2, SN0, 0, 0, 0); \
    SN1 = __builtin_amdgcn_mfma_f32_32x32x16_bf16(kc3_, bqh3, SN1, 0, 0, 0); \
    SN0 = __builtin_amdgcn_mfma_f32_32x32x16_bf16(kc2_, bql2, SN0, 0, 0, 0); \
    SN1 = __builtin_amdgcn_mfma_f32_32x32x16_bf16(kc3_, bql3, SN1, 0, 0, 0); \
    SN0 = __builtin_amdgcn_mfma_f32_32x32x16_bf16(kd2_, bqh2, SN0, 0, 0, 0); \
    SN1 = __builtin_amdgcn_mfma_f32_32x32x16_bf16(kd3_, bqh3, SN1, 0, 0, 0); \
} while (0)

#define SMPV(SC0, SC1, MWC, BPV) do { \
    const char* bv_ = (BPV); \
    const unsigned wm_ = (MWC) >> (hi << 2); \
    float p_[16]; \
    _Pragma("unroll") \
    for (int r_ = 0; r_ < 16; ++r_) { \
        float arg_ = fmaf(SC0[r_] + SC1[r_], 0.125f, -MFIX); \
        arg_ = ((wm_ >> ((r_ & 3) + ((r_ >> 2) << 3))) & 1u) ? arg_ : EPSC; \
        p_[r_] = __expf(arg_); \
    } \
    unsigned x0_, x1_, y0_, y1_, x2_, x3_, y2_, y3_; \
    asm("v_cvt_pk_bf16_f32 %0, %1, %2" : "=v"(x0_) : "v"(p_[0]),  "v"(p_[1])); \
    asm("v_cvt_pk_bf16_f32 %0, %1, %2" : "=v"(x1_) : "v"(p_[2]),  "v"(p_[3])); \
    asm("v_cvt_pk_bf16_f32 %0, %1, %2" : "=v"(y0_) : "v"(p_[4]),  "v"(p_[5])); \
    asm("v_cvt_pk_bf16_f32 %0, %1, %2" : "=v"(y1_) : "v"(p_[6]),  "v"(p_[7])); \
    asm volatile("v_permlane32_swap_b32 %0, %1" : "+v"(x0_), "+v"(y0_)); \
    asm volatile("v_permlane32_swap_b32 %0, %1" : "+v"(x1_), "+v"(y1_)); \
    u32x4 pw0_; pw0_[0] = x0_; pw0_[1] = x1_; pw0_[2] = y0_; pw0_[3] = y1_; \
    short8 pa0_ = __builtin_bit_cast(short8, pw0_); \
    asm("v_cvt_pk_bf16_f32 %0, %1, %2" : "=v"(x2_) : "v"(p_[8]),  "v"(p_[9])); \
    asm("v_cvt_pk_bf16_f32 %0, %1, %2" : "=v"(x3_) : "v"(p_[10]), "v"(p_[11])); \
    asm("v_cvt_pk_bf16_f32 %0, %1, %2" : "=v"(y2_) : "v"(p_[12]), "v"(p_[13])); \
    asm("v_cvt_pk_bf16_f32 %0, %1, %2" : "=v"(y3_) : "v"(p_[14]), "v"(p_[15])); \
    asm volatile("v_permlane32_swap_b32 %0, %1" : "+v"(x2_), "+v"(y2_)); \
    asm volatile("v_permlane32_swap_b32 %0, %1" : "+v"(x3_), "+v"(y3_)); \
    u32x4 pw1_; pw1_[0] = x2_; pw1_[1] = x3_; pw1_[2] = y2_; pw1_[3] = y3_; \
    short8 pa1_ = __builtin_bit_cast(short8, pw1_); \
    short8 v00_ = *(const short8*)(bv_ + voff0[0]); \
    short8 v01_ = *(const short8*)(bv_ + voff0[1]); \
    short8 v10_ = *(const short8*)(bv_ + voff1[0]); \
    short8 v11_ = *(const short8*)(bv_ + voff1[1]); \
    O0 = __builtin_amdgcn_mfma_f32_32x32x16_bf16(pa0_, v00_, O0, 0, 0, 0); \
    O0 = __builtin_amdgcn_mfma_f32_32x32x16_bf16(pa1_, v01_, O0, 0, 0, 0); \
    O1 = __builtin_amdgcn_mfma_f32_32x32x16_bf16(pa0_, v10_, O1, 0, 0, 0); \
    O1 = __builtin_amdgcn_mfma_f32_32x32x16_bf16(pa1_, v11_, O1, 0, 0, 0); \
    LS = __builtin_amdgcn_mfma_f32_32x32x16_bf16(pa0_, bones, LS, 0, 0, 0); \
    LS = __builtin_amdgcn_mfma_f32_32x32x16_bf16(pa1_, bones, LS, 0, 0, 0); \
} while (0)

#define ITER(KB, SC0, SC1, SN0, SN1, MWC, MWN) do { \
    asm volatile("s_waitcnt vmcnt(0)" ::: "memory"); \
    __builtin_amdgcn_sched_barrier(0); \
    __builtin_amdgcn_s_barrier(); \
    __builtin_amdgcn_sched_barrier(0); \
    MWN = mp[((KB) + 1) & 31]; \
    { const int kpf_ = ((KB) + 2 > 31) ? 31 : ((KB) + 2); \
      STAGE(kpf_, ((KB) + 2) % 3); } \
    QK((const char*)smem + (size_t)(((KB) + 1) % 3) * 12288, SN0, SN1); \
    SMPV(SC0, SC1, MWC, (const char*)smem + (size_t)((KB) % 3) * 12288); \
} while (0)

__global__ __launch_bounds__(128, 2) void attn_main(
        const u16* __restrict__ qh, const u16* __restrict__ ql,
        const u16* __restrict__ kh, const u16* __restrict__ kl,
        const u16* __restrict__ vt, const unsigned* __restrict__ mbits,
        float* __restrict__ out) {
    __shared__ __align__(16) unsigned char smem[3 * 12288];

    const int lane = threadIdx.x & 63;
    const int wave = threadIdx.x >> 6;
    const int l5 = lane & 31;
    const int hi = lane >> 5;

    // XCD-aware swizzle: XCD x serves bh in [8x, 8x+8)
    const int bid = blockIdx.x;
    const int bh = ((bid & 7) << 3) | (bid >> 7);
    const int qb = (bid >> 3) & 15;
    const int qrow0 = qb * 64 + wave * 32;

    // Q B-fragments: n = l5 = q-row, k = c*16 + hi*8 + j
    const u16* qhp = qh + ((size_t)bh * SEQ + qrow0 + l5) * DH + hi * 8;
    const u16* qlp = ql + ((size_t)bh * SEQ + qrow0 + l5) * DH + hi * 8;
    short8 bqh0 = *(const short8*)(qhp);
    short8 bqh1 = *(const short8*)(qhp + 16);
    short8 bqh2 = *(const short8*)(qhp + 32);
    short8 bqh3 = *(const short8*)(qhp + 48);
    short8 bql0 = *(const short8*)(qlp);
    short8 bql1 = *(const short8*)(qlp + 16);
    short8 bql2 = *(const short8*)(qlp + 32);
    short8 bql3 = *(const short8*)(qlp + 48);

    // staging sources (pre-swizzled per-lane)
    const char* khg = (const char*)(kh + (size_t)bh * SEQ * DH);
    const char* klg = (const char*)(kl + (size_t)bh * SEQ * DH);
    const char* vtg = (const char*)(vt + (size_t)bh * DH * SEQ);
    const size_t koffs = (size_t)(wave * 8 + (lane >> 3)) * 128
                       + (size_t)(((lane & 7) ^ (lane >> 3)) << 4);
    const size_t voffs = (size_t)(wave * 16 + (lane >> 2)) * (SEQ * 2)
                       + (size_t)(((lane & 3) ^ ((lane >> 3) & 3)) << 4);
    const char* khs = khg + koffs;
    const char* kls = klg + koffs;
    const char* vts = vtg + voffs;
    char* dbase = (char*)smem + wave * 1024;

    // LDS read offsets (r5-verified layouts)
    int koff[4], voff0[2], voff1[2];
#pragma unroll
    for (int c = 0; c < 4; ++c)
        koff[c] = l5 * 128 + ((((c << 1) | hi) ^ (l5 & 7)) << 4);
#pragma unroll
    for (int c = 0; c < 2; ++c) {
        const int s = (((c << 1) | hi) ^ ((l5 >> 1) & 3)) << 4;
        voff0[c] = 8192 + l5 * 64 + s;
        voff1[c] = 8192 + (32 + l5) * 64 + s;
    }

    const unsigned* mp = mbits + (size_t)(qrow0 + l5) * 32;

    f32x16 O0, O1, LS, ZR;
#pragma unroll
    for (int r = 0; r < 16; ++r) { O0[r] = 0.f; O1[r] = 0.f; LS[r] = 0.f; ZR[r] = 0.f; }
    short8 bones;
#pragma unroll
    for (int j = 0; j < 8; ++j) bones[j] = (short)0x3F80;

    f32x16 sA0, sA1, sB0, sB1;
    unsigned mwA, mwB;
    mwA = mp[0];

    // prologue: stage 0,1; wait stage0; QK(0)
    STAGE(0, 0);
    STAGE(1, 1);
    asm volatile("s_waitcnt vmcnt(6)" ::: "memory");
    __builtin_amdgcn_sched_barrier(0);
    __builtin_amdgcn_s_barrier();
    __builtin_amdgcn_sched_barrier(0);
    QK((const char*)smem, sA0, sA1);

#pragma unroll 1
    for (int kb = 0; kb < 30; kb += 2) {
        ITER(kb,     sA0, sA1, sB0, sB1, mwA, mwB);
        ITER(kb + 1, sB0, sB1, sA0, sA1, mwB, mwA);
    }
    // kb = 30: full body (stage clamps to 31; QK(31) from buf1)
    ITER(30, sA0, sA1, sB0, sB1, mwA, mwB);
    // kb = 31: no stage, no QK — just softmax+PV from buf[31%3=1]
    SMPV(sB0, sB1, mwB, (const char*)smem + 1 * 12288);

    // ---- epilogue: LS holds the denominator per reg-row (all lanes equal) ----
    float* op = out + ((size_t)bh * SEQ + qrow0) * DH;
#pragma unroll
    for (int r = 0; r < 16; ++r) {
        const int qr = (r & 3) + ((r >> 2) << 3) + (hi << 2);
        const float iv = 1.f / LS[r];
        op[(size_t)qr * DH + l5] = O0[r] * iv;
        op[(size_t)qr * DH + 32 + l5] = O1[r] * iv;
    }
}

extern "C" void kernel_launch(void* const* d_in, const int* in_sizes, int n_in,
                              void* d_out, int out_size, void* d_ws, size_t ws_size,
                              hipStream_t stream) {
    const float* q = (const float*)d_in[0];
    const float* k = (const float*)d_in[1];
    const float* v = (const float*)d_in[2];
    const int* mask = (const int*)d_in[3];
    float* out = (float*)d_out;

    char* w = (char*)d_ws;
    const size_t NQ = (size_t)BH * SEQ * DH;
    u16* qh = (u16*)(w);
    u16* ql = (u16*)(w + 2 * NQ);
    u16* kh = (u16*)(w + 4 * NQ);
    u16* kl = (u16*)(w + 6 * NQ);
    u16* vt = (u16*)(w + 8 * NQ);
    unsigned* mbits = (unsigned*)(w + 10 * NQ);

    prep_split<<<dim3((NQ / 4) / 256), dim3(256), 0, stream>>>(q, k, qh, ql, kh, kl);
    prep_vt<<<dim3(BH * 16), dim3(256), 0, stream>>>(v, vt);
    prep_mask<<<dim3((SEQ * 32) / 256), dim3(256), 0, stream>>>(mask, mbits);
    attn_main<<<dim3(BH * (SEQ / 64)), dim3(128), 0, stream>>>(qh, ql, kh, kl, vt, mbits, out);
}

// Round 7
// 54.539 us; speedup vs baseline: 4.0092x; 1.3564x over previous
//
#include <hip/hip_runtime.h>

#define BH 64
#define SEQ 1024
#define DH 64
#define EPSV 1e-6f
#define MFIX 8.3f   /* fixed softmax reference: p = e^(s - MFIX); exact for any m, scores |s|<8 w.h.p. */
#define EPSC (EPSV - MFIX)

typedef short short8 __attribute__((ext_vector_type(8)));
typedef float f32x4 __attribute__((ext_vector_type(4)));
typedef float f32x16 __attribute__((ext_vector_type(16)));
typedef unsigned u32x4 __attribute__((ext_vector_type(4)));
typedef unsigned short u16;
typedef unsigned short u16x4 __attribute__((ext_vector_type(4)));

__device__ __forceinline__ u16 f2bf(float x) {
    unsigned u = __builtin_bit_cast(unsigned, x);
    u += 0x7fffu + ((u >> 16) & 1u);   // round-to-nearest-even
    return (u16)(u >> 16);
}
__device__ __forceinline__ float bf2f(u16 h) {
    unsigned u = ((unsigned)h) << 16;
    return __builtin_bit_cast(float, u);
}
__device__ __forceinline__ void gload16(const void* g, void* l) {
    __builtin_amdgcn_global_load_lds(
        (const __attribute__((address_space(1))) void*)g,
        (__attribute__((address_space(3))) void*)l, 16, 0, 0);
}

// ---------------- fused prep: V->Vt bf16 transpose | K->bf16 | mask->bits ----------------
__global__ __launch_bounds__(256) void prep_all(
        const float* __restrict__ kf, const float* __restrict__ vf,
        const int* __restrict__ mask,
        u16* __restrict__ kb16, u16* __restrict__ vt, unsigned* __restrict__ bits) {
    __shared__ u16 tile[64][65];
    const int b = blockIdx.x;
    const int t = threadIdx.x;
    if (b < 1024) {
        // ---- V transpose: vt[bh][d][s] bf16 ----
        const int bh = b >> 4;
        const int st = b & 15;
        const int sl = t >> 2, c = t & 3;
        const float* src = vf + ((size_t)bh * SEQ + st * 64 + sl) * DH + c * 16;
#pragma unroll
        for (int q = 0; q < 4; ++q) {
            f32x4 x = *(const f32x4*)(src + q * 4);
#pragma unroll
            for (int j = 0; j < 4; ++j) tile[sl][c * 16 + q * 4 + j] = f2bf(x[j]);
        }
        __syncthreads();
        const int d = t >> 2, scn = t & 3;
        u16* dst = vt + ((size_t)bh * DH + d) * SEQ + st * 64 + scn * 16;
        short8 o0, o1;
#pragma unroll
        for (int j = 0; j < 8; ++j) o0[j] = (short)tile[scn * 16 + j][d];
#pragma unroll
        for (int j = 0; j < 8; ++j) o1[j] = (short)tile[scn * 16 + 8 + j][d];
        *(short8*)dst = o0;
        *(short8*)(dst + 8) = o1;
    } else if (b < 2048) {
        // ---- K convert: 16 elems / thread ----
        const size_t base = ((size_t)(b - 1024) * 256 + t) * 16;
#pragma unroll
        for (int j = 0; j < 4; ++j) {
            f32x4 x = *(const f32x4*)(kf + base + j * 4);
            u16x4 o;
#pragma unroll
            for (int i = 0; i < 4; ++i) o[i] = f2bf(x[i]);
            *(u16x4*)(kb16 + base + j * 4) = o;
        }
    } else {
        // ---- mask -> bitfield [S][32] u32 ----
        const int tt = (b - 2048) * 256 + t;   // 0..32767
        const int qr = tt >> 5, w = tt & 31;
        const int* src = mask + (size_t)qr * SEQ + w * 32;
        unsigned bb = 0;
#pragma unroll
        for (int j = 0; j < 32; ++j) bb |= (src[j] != 0 ? 1u : 0u) << j;
        bits[tt] = bb;
    }
}

// ---------------- main: 32x32 MFMA, QBLK=128 (4 waves), pipelined ----------------
// 3 LDS buffers x 8KB: [0,4K) K bf16 32x128B (slot^row&7), [4K,8K) vt 64x64B (slot^((d>>1)&3)).
// Per iter kb: vmcnt(0) [prev-iter loads] -> s_barrier -> stage(kb+2) ->
//              QK(kb+1) MFMA -> softmax(kb) VALU -> PV(kb) + ls-MFMA.
// Buffers in iter kb: {kb, kb+1, kb+2} distinct mod 3; barrier bounds skew. Safe.

#define STAGE(KB, BUF) do { \
    gload16(ks + ((size_t)(KB) << 12), kdst + (size_t)(BUF) * 8192); \
    gload16(vs + ((size_t)(KB) << 6),  vdst + (size_t)(BUF) * 8192); \
} while (0)

#define QK(BB, SN0, SN1) do { \
    const char* bq_ = (BB); \
    short8 kc0_ = *(const short8*)(bq_ + koff[0]); \
    short8 kc1_ = *(const short8*)(bq_ + koff[1]); \
    short8 kc2_ = *(const short8*)(bq_ + koff[2]); \
    short8 kc3_ = *(const short8*)(bq_ + koff[3]); \
    __builtin_amdgcn_s_setprio(1); \
    SN0 = __builtin_amdgcn_mfma_f32_32x32x16_bf16(kc0_, bqh[0], ZR, 0, 0, 0); \
    SN1 = __builtin_amdgcn_mfma_f32_32x32x16_bf16(kc1_, bqh[1], ZR, 0, 0, 0); \
    SN0 = __builtin_amdgcn_mfma_f32_32x32x16_bf16(kc0_, bql[0], SN0, 0, 0, 0); \
    SN1 = __builtin_amdgcn_mfma_f32_32x32x16_bf16(kc1_, bql[1], SN1, 0, 0, 0); \
    SN0 = __builtin_amdgcn_mfma_f32_32x32x16_bf16(kc2_, bqh[2], SN0, 0, 0, 0); \
    SN1 = __builtin_amdgcn_mfma_f32_32x32x16_bf16(kc3_, bqh[3], SN1, 0, 0, 0); \
    SN0 = __builtin_amdgcn_mfma_f32_32x32x16_bf16(kc2_, bql[2], SN0, 0, 0, 0); \
    SN1 = __builtin_amdgcn_mfma_f32_32x32x16_bf16(kc3_, bql[3], SN1, 0, 0, 0); \
    __builtin_amdgcn_s_setprio(0); \
} while (0)

#define SMPV(SC0, SC1, MWC, BPV) do { \
    const char* bv_ = (BPV); \
    const unsigned wm_ = (MWC) >> (hi << 2); \
    float p_[16]; \
    _Pragma("unroll") \
    for (int r_ = 0; r_ < 16; ++r_) { \
        float arg_ = fmaf(SC0[r_] + SC1[r_], 0.125f, -MFIX); \
        arg_ = ((wm_ >> ((r_ & 3) + ((r_ >> 2) << 3))) & 1u) ? arg_ : EPSC; \
        p_[r_] = __expf(arg_); \
    } \
    unsigned x0_, x1_, y0_, y1_, x2_, x3_, y2_, y3_; \
    asm("v_cvt_pk_bf16_f32 %0, %1, %2" : "=v"(x0_) : "v"(p_[0]),  "v"(p_[1])); \
    asm("v_cvt_pk_bf16_f32 %0, %1, %2" : "=v"(x1_) : "v"(p_[2]),  "v"(p_[3])); \
    asm("v_cvt_pk_bf16_f32 %0, %1, %2" : "=v"(y0_) : "v"(p_[4]),  "v"(p_[5])); \
    asm("v_cvt_pk_bf16_f32 %0, %1, %2" : "=v"(y1_) : "v"(p_[6]),  "v"(p_[7])); \
    asm volatile("v_permlane32_swap_b32 %0, %1" : "+v"(x0_), "+v"(y0_)); \
    asm volatile("v_permlane32_swap_b32 %0, %1" : "+v"(x1_), "+v"(y1_)); \
    u32x4 pw0_; pw0_[0] = x0_; pw0_[1] = x1_; pw0_[2] = y0_; pw0_[3] = y1_; \
    short8 pa0_ = __builtin_bit_cast(short8, pw0_); \
    asm("v_cvt_pk_bf16_f32 %0, %1, %2" : "=v"(x2_) : "v"(p_[8]),  "v"(p_[9])); \
    asm("v_cvt_pk_bf16_f32 %0, %1, %2" : "=v"(x3_) : "v"(p_[10]), "v"(p_[11])); \
    asm("v_cvt_pk_bf16_f32 %0, %1, %2" : "=v"(y2_) : "v"(p_[12]), "v"(p_[13])); \
    asm("v_cvt_pk_bf16_f32 %0, %1, %2" : "=v"(y3_) : "v"(p_[14]), "v"(p_[15])); \
    asm volatile("v_permlane32_swap_b32 %0, %1" : "+v"(x2_), "+v"(y2_)); \
    asm volatile("v_permlane32_swap_b32 %0, %1" : "+v"(x3_), "+v"(y3_)); \
    u32x4 pw1_; pw1_[0] = x2_; pw1_[1] = x3_; pw1_[2] = y2_; pw1_[3] = y3_; \
    short8 pa1_ = __builtin_bit_cast(short8, pw1_); \
    short8 v00_ = *(const short8*)(bv_ + voff0[0]); \
    short8 v01_ = *(const short8*)(bv_ + voff0[1]); \
    short8 v10_ = *(const short8*)(bv_ + voff1[0]); \
    short8 v11_ = *(const short8*)(bv_ + voff1[1]); \
    __builtin_amdgcn_s_setprio(1); \
    O0 = __builtin_amdgcn_mfma_f32_32x32x16_bf16(pa0_, v00_, O0, 0, 0, 0); \
    O0 = __builtin_amdgcn_mfma_f32_32x32x16_bf16(pa1_, v01_, O0, 0, 0, 0); \
    O1 = __builtin_amdgcn_mfma_f32_32x32x16_bf16(pa0_, v10_, O1, 0, 0, 0); \
    O1 = __builtin_amdgcn_mfma_f32_32x32x16_bf16(pa1_, v11_, O1, 0, 0, 0); \
    LS = __builtin_amdgcn_mfma_f32_32x32x16_bf16(pa0_, bones, LS, 0, 0, 0); \
    LS = __builtin_amdgcn_mfma_f32_32x32x16_bf16(pa1_, bones, LS, 0, 0, 0); \
    __builtin_amdgcn_s_setprio(0); \
} while (0)

#define ITER(KB, SC0, SC1, SN0, SN1, MWC, MWN) do { \
    asm volatile("s_waitcnt vmcnt(0)" ::: "memory"); \
    __builtin_amdgcn_sched_barrier(0); \
    __builtin_amdgcn_s_barrier(); \
    __builtin_amdgcn_sched_barrier(0); \
    MWN = mp[((KB) + 1) & 31]; \
    { const int kpf_ = ((KB) + 2 > 31) ? 31 : ((KB) + 2); \
      STAGE(kpf_, ((KB) + 2) % 3); } \
    QK((const char*)smem + (size_t)(((KB) + 1) % 3) * 8192, SN0, SN1); \
    SMPV(SC0, SC1, MWC, (const char*)smem + (size_t)((KB) % 3) * 8192); \
} while (0)

__global__ __launch_bounds__(256, 2) void attn_main(
        const float* __restrict__ q, const u16* __restrict__ kb16,
        const u16* __restrict__ vt, const unsigned* __restrict__ mbits,
        float* __restrict__ out) {
    __shared__ __align__(16) unsigned char smem[3 * 8192];

    const int lane = threadIdx.x & 63;
    const int wave = threadIdx.x >> 6;
    const int l5 = lane & 31;
    const int hi = lane >> 5;

    // XCD-aware: XCD x (bid&7) serves bh in [8x, 8x+8); bijective over 512 blocks
    const int bid = blockIdx.x;
    const int bh = ((bid & 7) << 3) | ((bid >> 3) & 7);
    const int qb = bid >> 6;                 // 0..7
    const int qrow0 = qb * 128 + wave * 32;

    // ---- Q: fp32 load + hi/lo bf16 split, in registers ----
    const float* qp = q + ((size_t)bh * SEQ + qrow0 + l5) * DH + hi * 8;
    short8 bqh[4], bql[4];
#pragma unroll
    for (int c = 0; c < 4; ++c) {
        f32x4 x0 = *(const f32x4*)(qp + c * 16);
        f32x4 x1 = *(const f32x4*)(qp + c * 16 + 4);
        short8 h, l;
#pragma unroll
        for (int j = 0; j < 4; ++j) {
            u16 h0 = f2bf(x0[j]); h[j] = (short)h0; l[j] = (short)f2bf(x0[j] - bf2f(h0));
            u16 h1 = f2bf(x1[j]); h[4 + j] = (short)h1; l[4 + j] = (short)f2bf(x1[j] - bf2f(h1));
        }
        bqh[c] = h; bql[c] = l;
    }

    // ---- staging sources (pre-swizzled per-lane; rule both-sides-or-neither) ----
    const char* kg = (const char*)(kb16 + (size_t)bh * SEQ * DH);
    const char* vg = (const char*)(vt + (size_t)bh * DH * SEQ);
    const size_t koffs = (size_t)(wave * 8 + (lane >> 3)) * 128
                       + (size_t)(((lane & 7) ^ (lane >> 3)) << 4);
    const size_t voffs = (size_t)(wave * 16 + (lane >> 2)) * (SEQ * 2)
                       + (size_t)(((lane & 3) ^ ((lane >> 3) & 3)) << 4);
    const char* ks = kg + koffs;
    const char* vs = vg + voffs;
    char* kdst = (char*)smem + wave * 1024;
    char* vdst = (char*)smem + 4096 + wave * 1024;

    // ---- LDS read offsets (r5-verified swizzles) ----
    int koff[4], voff0[2], voff1[2];
#pragma unroll
    for (int c = 0; c < 4; ++c)
        koff[c] = l5 * 128 + ((((c << 1) | hi) ^ (l5 & 7)) << 4);
#pragma unroll
    for (int c = 0; c < 2; ++c) {
        const int s = (((c << 1) | hi) ^ ((l5 >> 1) & 3)) << 4;
        voff0[c] = 4096 + l5 * 64 + s;
        voff1[c] = 4096 + (32 + l5) * 64 + s;
    }

    const unsigned* mp = mbits + (size_t)(qrow0 + l5) * 32;

    f32x16 O0, O1, LS, ZR;
#pragma unroll
    for (int r = 0; r < 16; ++r) { O0[r] = 0.f; O1[r] = 0.f; LS[r] = 0.f; ZR[r] = 0.f; }
    short8 bones;
#pragma unroll
    for (int j = 0; j < 8; ++j) bones[j] = (short)0x3F80;

    f32x16 sA0, sA1, sB0, sB1;
    unsigned mwA, mwB;
    mwA = mp[0];

    // prologue: stage 0,1; wait stage0 (oldest 3 of 5 outstanding); QK(0)
    STAGE(0, 0);
    STAGE(1, 1);
    asm volatile("s_waitcnt vmcnt(2)" ::: "memory");
    __builtin_amdgcn_sched_barrier(0);
    __builtin_amdgcn_s_barrier();
    __builtin_amdgcn_sched_barrier(0);
    QK((const char*)smem, sA0, sA1);

#pragma unroll 1
    for (int kb = 0; kb < 30; kb += 2) {
        ITER(kb,     sA0, sA1, sB0, sB1, mwA, mwB);
        ITER(kb + 1, sB0, sB1, sA0, sA1, mwB, mwA);
    }
    ITER(30, sA0, sA1, sB0, sB1, mwA, mwB);
    // kb = 31: no stage, no QK — softmax+PV from buf[31%3=1]
    SMPV(sB0, sB1, mwB, (const char*)smem + 1 * 8192);

    // ---- epilogue: LS holds the denominator per reg-row (all lanes equal) ----
    float* op = out + ((size_t)bh * SEQ + qrow0) * DH;
#pragma unroll
    for (int r = 0; r < 16; ++r) {
        const int qr = (r & 3) + ((r >> 2) << 3) + (hi << 2);
        const float iv = 1.f / LS[r];
        op[(size_t)qr * DH + l5] = O0[r] * iv;
        op[(size_t)qr * DH + 32 + l5] = O1[r] * iv;
    }
}

extern "C" void kernel_launch(void* const* d_in, const int* in_sizes, int n_in,
                              void* d_out, int out_size, void* d_ws, size_t ws_size,
                              hipStream_t stream) {
    const float* q = (const float*)d_in[0];
    const float* k = (const float*)d_in[1];
    const float* v = (const float*)d_in[2];
    const int* mask = (const int*)d_in[3];
    float* out = (float*)d_out;

    char* w = (char*)d_ws;
    const size_t NQ = (size_t)BH * SEQ * DH;          // 4,194,304 elements
    u16* kb16 = (u16*)(w);                             // 8 MB
    u16* vt = (u16*)(w + 2 * NQ);                      // 8 MB
    unsigned* mbits = (unsigned*)(w + 4 * NQ);         // 128 KB

    prep_all<<<dim3(2176), dim3(256), 0, stream>>>(k, v, mask, kb16, vt, mbits);
    attn_main<<<dim3(512), dim3(256), 0, stream>>>(q, kb16, vt, mbits, out);
}

// Round 12
// 50.881 us; speedup vs baseline: 4.2975x; 1.0719x over previous
//
#include <hip/hip_runtime.h>

#define BH 64
#define SEQ 1024
#define DH 64
#define EPSV 1e-6f
#define MFIX 8.3f   /* fixed softmax reference: p = e^(s - MFIX); exact for any m, scores |s|<8 w.h.p. */
#define EPSC (EPSV - MFIX)

typedef short short8 __attribute__((ext_vector_type(8)));
typedef float f32x4 __attribute__((ext_vector_type(4)));
typedef float f32x16 __attribute__((ext_vector_type(16)));
typedef unsigned u32x4 __attribute__((ext_vector_type(4)));
typedef unsigned short u16;
typedef unsigned short u16x4 __attribute__((ext_vector_type(4)));

__device__ __forceinline__ u16 f2bf(float x) {
    unsigned u = __builtin_bit_cast(unsigned, x);
    u += 0x7fffu + ((u >> 16) & 1u);   // round-to-nearest-even
    return (u16)(u >> 16);
}
__device__ __forceinline__ void gload16(const void* g, void* l) {
    __builtin_amdgcn_global_load_lds(
        (const __attribute__((address_space(1))) void*)g,
        (__attribute__((address_space(3))) void*)l, 16, 0, 0);
}

// ---------------- fused prep: V->Vt bf16 transpose | K->bf16 | mask->bits ----------------
__global__ __launch_bounds__(256) void prep_all(
        const float* __restrict__ kf, const float* __restrict__ vf,
        const int* __restrict__ mask,
        u16* __restrict__ kb16, u16* __restrict__ vt, unsigned* __restrict__ bits) {
    __shared__ u16 tile[64][65];
    const int b = blockIdx.x;
    const int t = threadIdx.x;
    if (b < 1024) {
        // ---- V transpose: vt[bh][d][s] bf16 ----
        const int bh = b >> 4;
        const int st = b & 15;
        const int sl = t >> 2, c = t & 3;
        const float* src = vf + ((size_t)bh * SEQ + st * 64 + sl) * DH + c * 16;
#pragma unroll
        for (int q = 0; q < 4; ++q) {
            f32x4 x = *(const f32x4*)(src + q * 4);
#pragma unroll
            for (int j = 0; j < 4; ++j) tile[sl][c * 16 + q * 4 + j] = f2bf(x[j]);
        }
        __syncthreads();
        const int d = t >> 2, scn = t & 3;
        u16* dst = vt + ((size_t)bh * DH + d) * SEQ + st * 64 + scn * 16;
        short8 o0, o1;
#pragma unroll
        for (int j = 0; j < 8; ++j) o0[j] = (short)tile[scn * 16 + j][d];
#pragma unroll
        for (int j = 0; j < 8; ++j) o1[j] = (short)tile[scn * 16 + 8 + j][d];
        *(short8*)dst = o0;
        *(short8*)(dst + 8) = o1;
    } else if (b < 2048) {
        // ---- K convert: 16 elems / thread ----
        const size_t base = ((size_t)(b - 1024) * 256 + t) * 16;
#pragma unroll
        for (int j = 0; j < 4; ++j) {
            f32x4 x = *(const f32x4*)(kf + base + j * 4);
            u16x4 o;
#pragma unroll
            for (int i = 0; i < 4; ++i) o[i] = f2bf(x[i]);
            *(u16x4*)(kb16 + base + j * 4) = o;
        }
    } else {
        // ---- mask -> bitfield [S][32] u32 ----
        const int tt = (b - 2048) * 256 + t;   // 0..32767
        const int qr = tt >> 5, w = tt & 31;
        const int* src = mask + (size_t)qr * SEQ + w * 32;
        unsigned bb = 0;
#pragma unroll
        for (int j = 0; j < 32; ++j) bb |= (src[j] != 0 ? 1u : 0u) << j;
        bits[tt] = bb;
    }
}

// ---------------- main: 32x32 MFMA, split-KV (wave pairs), 4 waves/SIMD ----------------
// Block 256 thr = 4 waves: wave w -> q-subtile (w&1), kv-half (w>>1).
// LDS: 2 bufs x [2 halves x (4KB K + 4KB V)] = 32KB. K rows 32x128B slot^(row&7) swizzle,
// V rows 64x64B slot^((d>>1)&3) swizzle; both applied pre-swizzled-source + swizzled-read.
// Schedule (2-phase): vmcnt(0) -> barrier -> stage(t+1) -> QK(t) -> softmax(t) -> PV(t).
// Merge: fixed-m softmax => halves combine by pure addition of O and denominators.
// Denominator is PER Q-ROW: lane's scalar ls covers q-row l5 (score layout), but PV output
// reg r covers q-row (r&3)+8(r>>2)+4hi — route ls through an LDS table indexed by q-row.

#define STAGE(T, BUF) do { \
    const size_t bo_ = (size_t)(BUF) * 16384; \
    const size_t tk_ = (size_t)(T) << 12; \
    const size_t tv_ = (size_t)(T) << 6; \
    gload16(ks0 + tk_, sd0 + bo_); \
    gload16(vs0 + tv_, sd1 + bo_); \
    gload16(ks1 + tk_, sd2 + bo_); \
    gload16(vs1 + tv_, sd3 + bo_); \
} while (0)

#define ITER(T, MWC, MWN) do { \
    asm volatile("s_waitcnt vmcnt(0)" ::: "memory"); \
    __builtin_amdgcn_sched_barrier(0); \
    __builtin_amdgcn_s_barrier(); \
    __builtin_amdgcn_sched_barrier(0); \
    MWN = mp[mbase + (((T) + 1 < 16) ? (T) + 1 : 15)]; \
    if ((T) < 15) STAGE((T) + 1, ((T) + 1) & 1); \
    const char* bb_ = (const char*)smem + (size_t)((T) & 1) * 16384; \
    short8 kc0_ = *(const short8*)(bb_ + koff[0]); \
    short8 kc1_ = *(const short8*)(bb_ + koff[1]); \
    short8 kc2_ = *(const short8*)(bb_ + koff[2]); \
    short8 kc3_ = *(const short8*)(bb_ + koff[3]); \
    f32x16 sn_; \
    _Pragma("unroll") \
    for (int z_ = 0; z_ < 16; ++z_) sn_[z_] = 0.f; \
    __builtin_amdgcn_s_setprio(1); \
    sn_ = __builtin_amdgcn_mfma_f32_32x32x16_bf16(kc0_, bqh0, sn_, 0, 0, 0); \
    sn_ = __builtin_amdgcn_mfma_f32_32x32x16_bf16(kc1_, bqh1, sn_, 0, 0, 0); \
    sn_ = __builtin_amdgcn_mfma_f32_32x32x16_bf16(kc2_, bqh2, sn_, 0, 0, 0); \
    sn_ = __builtin_amdgcn_mfma_f32_32x32x16_bf16(kc3_, bqh3, sn_, 0, 0, 0); \
    __builtin_amdgcn_s_setprio(0); \
    const unsigned wm_ = (MWC) >> (hi << 2); \
    float p_[16]; \
    _Pragma("unroll") \
    for (int r_ = 0; r_ < 16; ++r_) { \
        float arg_ = fmaf(sn_[r_], 0.125f, -MFIX); \
        arg_ = ((wm_ >> ((r_ & 3) + ((r_ >> 2) << 3))) & 1u) ? arg_ : EPSC; \
        p_[r_] = __expf(arg_); \
    } \
    ls += (((p_[0] + p_[1]) + (p_[2] + p_[3])) + ((p_[4] + p_[5]) + (p_[6] + p_[7]))) \
        + (((p_[8] + p_[9]) + (p_[10] + p_[11])) + ((p_[12] + p_[13]) + (p_[14] + p_[15]))); \
    unsigned x0_, x1_, y0_, y1_, x2_, x3_, y2_, y3_; \
    asm("v_cvt_pk_bf16_f32 %0, %1, %2" : "=v"(x0_) : "v"(p_[0]),  "v"(p_[1])); \
    asm("v_cvt_pk_bf16_f32 %0, %1, %2" : "=v"(x1_) : "v"(p_[2]),  "v"(p_[3])); \
    asm("v_cvt_pk_bf16_f32 %0, %1, %2" : "=v"(y0_) : "v"(p_[4]),  "v"(p_[5])); \
    asm("v_cvt_pk_bf16_f32 %0, %1, %2" : "=v"(y1_) : "v"(p_[6]),  "v"(p_[7])); \
    asm volatile("v_permlane32_swap_b32 %0, %1" : "+v"(x0_), "+v"(y0_)); \
    asm volatile("v_permlane32_swap_b32 %0, %1" : "+v"(x1_), "+v"(y1_)); \
    u32x4 pw0_; pw0_[0] = x0_; pw0_[1] = x1_; pw0_[2] = y0_; pw0_[3] = y1_; \
    short8 pa0_ = __builtin_bit_cast(short8, pw0_); \
    asm("v_cvt_pk_bf16_f32 %0, %1, %2" : "=v"(x2_) : "v"(p_[8]),  "v"(p_[9])); \
    asm("v_cvt_pk_bf16_f32 %0, %1, %2" : "=v"(x3_) : "v"(p_[10]), "v"(p_[11])); \
    asm("v_cvt_pk_bf16_f32 %0, %1, %2" : "=v"(y2_) : "v"(p_[12]), "v"(p_[13])); \
    asm("v_cvt_pk_bf16_f32 %0, %1, %2" : "=v"(y3_) : "v"(p_[14]), "v"(p_[15])); \
    asm volatile("v_permlane32_swap_b32 %0, %1" : "+v"(x2_), "+v"(y2_)); \
    asm volatile("v_permlane32_swap_b32 %0, %1" : "+v"(x3_), "+v"(y3_)); \
    u32x4 pw1_; pw1_[0] = x2_; pw1_[1] = x3_; pw1_[2] = y2_; pw1_[3] = y3_; \
    short8 pa1_ = __builtin_bit_cast(short8, pw1_); \
    short8 v00_ = *(const short8*)(bb_ + voff0[0]); \
    short8 v01_ = *(const short8*)(bb_ + voff0[1]); \
    short8 v10_ = *(const short8*)(bb_ + voff1[0]); \
    short8 v11_ = *(const short8*)(bb_ + voff1[1]); \
    __builtin_amdgcn_s_setprio(1); \
    O0 = __builtin_amdgcn_mfma_f32_32x32x16_bf16(pa0_, v00_, O0, 0, 0, 0); \
    O0 = __builtin_amdgcn_mfma_f32_32x32x16_bf16(pa1_, v01_, O0, 0, 0, 0); \
    O1 = __builtin_amdgcn_mfma_f32_32x32x16_bf16(pa0_, v10_, O1, 0, 0, 0); \
    O1 = __builtin_amdgcn_mfma_f32_32x32x16_bf16(pa1_, v11_, O1, 0, 0, 0); \
    __builtin_amdgcn_s_setprio(0); \
} while (0)

__global__ __launch_bounds__(256, 4) void attn_main(
        const float* __restrict__ q, const u16* __restrict__ kb16,
        const u16* __restrict__ vt, const unsigned* __restrict__ mbits,
        float* __restrict__ out) {
    __shared__ __align__(16) unsigned char smem[2 * 16384];

    const int t = threadIdx.x;
    const int lane = t & 63;
    const int wave = t >> 6;
    const int l5 = lane & 31;
    const int hi = lane >> 5;
    const int wq = wave & 1;       // q-subtile
    const int half = wave >> 1;    // kv-half

    // XCD-aware: xcd = bid&7 serves bh in [8x, 8x+8); bijective over 1024 blocks
    const int bid = blockIdx.x;
    const int bh = ((bid & 7) << 3) | ((bid >> 3) & 7);
    const int qb = bid >> 6;                  // 0..15
    const int qrow0 = qb * 64 + wq * 32;

    // ---- Q: fp32 load -> bf16 B-fragments (n = l5 = q-row, k = c*16 + hi*8 + j) ----
    const float* qp = q + ((size_t)bh * SEQ + qrow0 + l5) * DH + hi * 8;
    short8 bqh0, bqh1, bqh2, bqh3;
    {
        short8 hh[4];
#pragma unroll
        for (int c = 0; c < 4; ++c) {
            f32x4 x0 = *(const f32x4*)(qp + c * 16);
            f32x4 x1 = *(const f32x4*)(qp + c * 16 + 4);
#pragma unroll
            for (int j = 0; j < 4; ++j) {
                hh[c][j] = (short)f2bf(x0[j]);
                hh[c][4 + j] = (short)f2bf(x1[j]);
            }
        }
        bqh0 = hh[0]; bqh1 = hh[1]; bqh2 = hh[2]; bqh3 = hh[3];
    }

    // ---- staging sources (pre-swizzled per-lane; both-sides-or-neither) ----
    const char* kg = (const char*)(kb16 + (size_t)bh * SEQ * DH);
    const char* vg = (const char*)(vt + (size_t)bh * DH * SEQ);
    const char* ks0 = kg + (size_t)(t >> 3) * 128 + (size_t)(((t & 7) ^ ((t >> 3) & 7)) << 4);
    const char* ks1 = ks0 + 512 * 128;    // kv-half 1 keys
    const char* vs0 = vg + (size_t)(t >> 2) * (SEQ * 2) + (size_t)(((t & 3) ^ ((t >> 3) & 3)) << 4);
    const char* vs1 = vs0 + 512 * 2;      // kv-half 1 s-columns
    // LDS dests (wave-uniform base + lane*16, linear)
    char* sd0 = (char*)smem + wave * 1024;          // K half0
    char* sd1 = sd0 + 4096;                          // V half0
    char* sd2 = sd0 + 8192;                          // K half1
    char* sd3 = sd0 + 12288;                         // V half1

    // ---- LDS read offsets (this wave reads only its half) ----
    const int hb = half * 8192;
    int koff[4], voff0[2], voff1[2];
#pragma unroll
    for (int c = 0; c < 4; ++c)
        koff[c] = hb + l5 * 128 + ((((c << 1) | hi) ^ (l5 & 7)) << 4);
#pragma unroll
    for (int c = 0; c < 2; ++c) {
        const int s = (((c << 1) | hi) ^ ((l5 >> 1) & 3)) << 4;
        voff0[c] = hb + 4096 + l5 * 64 + s;
        voff1[c] = hb + 4096 + (32 + l5) * 64 + s;
    }

    const unsigned* mp = mbits + (size_t)(qrow0 + l5) * 32;
    const int mbase = half * 16;

    f32x16 O0, O1;
#pragma unroll
    for (int r = 0; r < 16; ++r) { O0[r] = 0.f; O1[r] = 0.f; }
    float ls = 0.f;

    unsigned mwA = mp[mbase], mwB;
    STAGE(0, 0);

#pragma unroll 1
    for (int tt = 0; tt < 14; tt += 2) {
        ITER(tt,     mwA, mwB);
        ITER(tt + 1, mwB, mwA);
    }
    ITER(14, mwA, mwB);
    ITER(15, mwB, mwA);

    // ---- merge the two kv-halves (fixed-m: pure addition), per-q-row denominators ----
    const float lsh = ls + __shfl_xor(ls, 32);   // this half's denominator for q-row qrow0+l5
    __syncthreads();                              // all LDS reads of buffers done; reuse smem
    float* lsums = (float*)smem;                  // [wq][half][32] = 128 floats
    float* osc   = (float*)((char*)smem + 512);   // [wq*64+lane][33] floats (padded stride)
    if (hi == 0) lsums[(wq * 2 + half) * 32 + l5] = lsh;
    if (wave >= 2) {
        float* dst = osc + ((size_t)(wq * 64) + lane) * 33;
#pragma unroll
        for (int r = 0; r < 16; ++r) { dst[r] = O0[r]; dst[16 + r] = O1[r]; }
    }
    __syncthreads();
    if (wave < 2) {
        const float* src = osc + ((size_t)(wq * 64) + lane) * 33;
        const float* lrow = lsums + wq * 64;      // [half][32]
        float* op = out + ((size_t)bh * SEQ + qrow0) * DH;
#pragma unroll
        for (int r = 0; r < 16; ++r) {
            const int qr = (r & 3) + ((r >> 2) << 3) + (hi << 2);
            const float iv = 1.f / (lrow[qr] + lrow[32 + qr]);
            op[(size_t)qr * DH + l5]      = (O0[r] + src[r]) * iv;
            op[(size_t)qr * DH + 32 + l5] = (O1[r] + src[16 + r]) * iv;
        }
    }
}

extern "C" void kernel_launch(void* const* d_in, const int* in_sizes, int n_in,
                              void* d_out, int out_size, void* d_ws, size_t ws_size,
                              hipStream_t stream) {
    const float* q = (const float*)d_in[0];
    const float* k = (const float*)d_in[1];
    const float* v = (const float*)d_in[2];
    const int* mask = (const int*)d_in[3];
    float* out = (float*)d_out;

    char* w = (char*)d_ws;
    const size_t NQ = (size_t)BH * SEQ * DH;          // 4,194,304 elements
    u16* kb16 = (u16*)(w);                             // 8 MB
    u16* vt = (u16*)(w + 2 * NQ);                      // 8 MB
    unsigned* mbits = (unsigned*)(w + 4 * NQ);         // 128 KB

    prep_all<<<dim3(2176), dim3(256), 0, stream>>>(k, v, mask, kb16, vt, mbits);
    attn_main<<<dim3(1024), dim3(256), 0, stream>>>(q, kb16, vt, mbits, out);
}